// Round 6
// baseline (518.580 us; speedup 1.0000x reference)
//
#include <hip/hip_runtime.h>
#include <hip/hip_fp16.h>
#include <float.h>

#define B 8
#define C 64
#define N 4096
#define O 64
#define KMAX 32
#define KC 32   // approx candidate count (exact top-k set re-selected from these)

typedef unsigned short u16;
typedef __attribute__((ext_vector_type(8))) u16 u16x8;
typedef __attribute__((ext_vector_type(8))) short bf16x8;
typedef __attribute__((ext_vector_type(4))) float f32x4;

__device__ __forceinline__ u16 f2bf(float f) {
    unsigned u = __builtin_bit_cast(unsigned, f);
    unsigned r = (u + 0x7FFFu + ((u >> 16) & 1)) >> 16;   // RTNE
    return (u16)r;
}

// ---------- fused prep: xt fp32, xtb bf16, xx, u/v fp16 ----------
__global__ __launch_bounds__(256) void ec_prep(const float* __restrict__ x,
                                               const float* __restrict__ W,
                                               float* __restrict__ xx,
                                               float* __restrict__ xt,
                                               u16* __restrict__ xtb,
                                               __half* __restrict__ u,
                                               __half* __restrict__ v) {
    __shared__ float xs[64][65];
    __shared__ float W1[C][64];
    __shared__ float Wd[C][64];
    __shared__ float rs[4][64];
    const int blk = blockIdx.x;            // B*N/64 = 512
    const int b = blk >> 6;
    const int n0 = (blk & 63) << 6;
    const int t = threadIdx.x;
#pragma unroll
    for (int p = 0; p < 16; ++p) {
        int q = t + 256 * p; int c = q >> 6, j = q & 63;
        xs[c][j] = x[(size_t)b * C * N + (size_t)c * N + n0 + j];
    }
#pragma unroll
    for (int p = 0; p < 16; ++p) {
        int q = t + 256 * p; int c = q >> 6, o = q & 63;
        float w1 = W[o * 128 + c];
        float w2 = W[o * 128 + 64 + c];
        W1[c][o] = w1; Wd[c][o] = w2 - w1;
    }
    __syncthreads();
    {
        const int j = t >> 2, g = t & 3;
        float vals[16]; float ss = 0.f;
#pragma unroll
        for (int i = 0; i < 16; ++i) { float f = xs[g * 16 + i][j]; vals[i] = f; ss += f * f; }
        rs[g][j] = ss;
        size_t rowb = ((size_t)b * N + n0 + j) * 64 + g * 16;
#pragma unroll
        for (int i = 0; i < 4; ++i) {
            float4 v4 = { vals[4 * i], vals[4 * i + 1], vals[4 * i + 2], vals[4 * i + 3] };
            *(float4*)&xt[rowb + 4 * i] = v4;
        }
        u16x8 h0, h1;
#pragma unroll
        for (int i = 0; i < 8; ++i) { h0[i] = f2bf(vals[i]); h1[i] = f2bf(vals[8 + i]); }
        *(u16x8*)&xtb[rowb] = h0;
        *(u16x8*)&xtb[rowb + 8] = h1;
    }
    {
        const int o = t & 63, ji = t >> 6;
#pragma unroll 1
        for (int p = 0; p < 16; ++p) {
            int j = ji + 4 * p;
            float su = 0.f, sv = 0.f;
#pragma unroll
            for (int c = 0; c < C; ++c) {
                float xv = xs[c][j];
                su += xv * W1[c][o];
                sv += xv * Wd[c][o];
            }
            size_t base = ((size_t)b * N + n0 + j) * O + o;
            u[base] = __float2half(su);
            v[base] = __float2half(sv);
        }
    }
    __syncthreads();
    if (t < 64) xx[(size_t)b * N + t + n0] = rs[0][t] + rs[1][t] + rs[2][t] + rs[3][t];
}

// ---------- MFMA distance -> SORTABLE u16 keys: dbf[zz][n][m] ----------
__global__ __launch_bounds__(256) void ec_gemm(const u16* __restrict__ xtb,
                                               const float* __restrict__ xx,
                                               u16* __restrict__ dbf, int b0) {
    __shared__ u16 lds[18432 + 8];
    const int t = threadIdx.x;
    const int m0 = blockIdx.x * 128, n0 = blockIdx.y * 128;
    const int zz = blockIdx.z, b = b0 + zz;
    const u16* xa = xtb + (size_t)b * N * 64;
#pragma unroll
    for (int p = 0; p < 4; ++p) {
        int q = t + 256 * p;
        int row = q >> 3, ch = q & 7;
        int by = (row * 128 + ch * 16) ^ ((row & 7) << 4);
        *(u16x8*)((char*)lds + by) = *(const u16x8*)&xa[(size_t)(n0 + row) * 64 + ch * 8];
        *(u16x8*)((char*)lds + 16384 + by) = *(const u16x8*)&xa[(size_t)(m0 + row) * 64 + ch * 8];
    }
    __syncthreads();
    const int w = t >> 6, lane = t & 63;
    const int wr = w >> 1, wc = w & 1;
    const int fr = lane & 15, fg = lane >> 4;
    f32x4 acc[4][4] = {};
#pragma unroll
    for (int ks = 0; ks < 2; ++ks) {
        bf16x8 af[4], bg[4];
#pragma unroll
        for (int fi = 0; fi < 4; ++fi) {
            int rowA = 64 * wr + 16 * fi + fr;
            int byA = (rowA * 128 + ks * 64 + fg * 16) ^ ((rowA & 7) << 4);
            af[fi] = *(const bf16x8*)((const char*)lds + byA);
            int rowB = 64 * wc + 16 * fi + fr;
            int byB = (rowB * 128 + ks * 64 + fg * 16) ^ ((rowB & 7) << 4);
            bg[fi] = *(const bf16x8*)((const char*)lds + 16384 + byB);
        }
#pragma unroll
        for (int fi = 0; fi < 4; ++fi)
#pragma unroll
            for (int fj = 0; fj < 4; ++fj)
                acc[fi][fj] = __builtin_amdgcn_mfma_f32_16x16x32_bf16(af[fi], bg[fj], acc[fi][fj], 0, 0, 0);
    }
    float xm[4];
#pragma unroll
    for (int fj = 0; fj < 4; ++fj) xm[fj] = xx[(size_t)b * N + m0 + 64 * wc + 16 * fj + fr];
    __syncthreads();
    u16* ep = lds + w * 64 * 72;
#pragma unroll
    for (int fi = 0; fi < 4; ++fi)
#pragma unroll
        for (int fj = 0; fj < 4; ++fj)
#pragma unroll
            for (int r = 0; r < 4; ++r) {
                float dv = 2.f * acc[fi][fj][r] - xm[fj];
                unsigned fu = __builtin_bit_cast(unsigned, dv);
                unsigned sf = fu ^ (unsigned)(((int)fu >> 31) | 0x80000000);
                int row = 16 * fi + fg * 4 + r, col = 16 * fj + fr;
                ep[row * 72 + col] = (u16)((sf + 0x8000u) >> 16);   // rounded sortable key
            }
    __syncthreads();
    const int rr = lane >> 3, cc = lane & 7;
#pragma unroll
    for (int p = 0; p < 8; ++p) {
        int row = p * 8 + rr;
        u16x8 vv = *(const u16x8*)&ep[row * 72 + cc * 8];
        *(u16x8*)&dbf[(size_t)zz * N * N + (size_t)(n0 + 64 * wr + row) * N + m0 + 64 * wc + cc * 8] = vv;
    }
}

// ---------- fused top-k + exact rescore + BN stats gather ----------
// Wave = 1 row. Row data register-resident (32 VGPR) with 64-bit alive mask.
__global__ __launch_bounds__(256) void ec_topk(const u16* __restrict__ dbf,
                                               const float* __restrict__ xt,
                                               const float* __restrict__ xx,
                                               const __half* __restrict__ u,
                                               const __half* __restrict__ v,
                                               const int* __restrict__ kptr,
                                               __half2* __restrict__ ext,
                                               float* __restrict__ stats, int b0) {
    __shared__ float sxn[4][64];
    __shared__ float rsum[256], rsum2[256];
    const int t = threadIdx.x, w = t >> 6, lane = t & 63;
    const int zz = blockIdx.y, b = b0 + zz;
    const int n = blockIdx.x * 4 + w;
    const int k = *kptr;
    const u16* drow = dbf + (size_t)zz * N * N + (size_t)n * N;

    // load sortable row chunk into regs + per-lane top-2 packed keys
    u16x8 s8[8];
    unsigned k1 = 0, k2 = 0;
#pragma unroll
    for (int p = 0; p < 8; ++p) {
        int c8 = lane + (p << 6);
        s8[p] = *(const u16x8*)&drow[c8 * 8];
#pragma unroll
        for (int jj = 0; jj < 8; ++jj) {
            unsigned key = ((unsigned)s8[p][jj] << 12) | (unsigned)(c8 * 8 + jj);
            if (key > k2) { if (key > k1) { k2 = k1; k1 = key; } else k2 = key; }
        }
    }
    unsigned long long alive = ~0ull;
    int my_cand = 0;
#pragma unroll 1
    for (int r = 0; r < KC; ++r) {
        unsigned bk = k1;
#pragma unroll
        for (int off = 1; off < 64; off <<= 1) {
            unsigned ov = __shfl_xor(bk, off);
            bk = bk > ov ? bk : ov;
        }
        int m = (int)(bk & 0xFFFu);
        if (lane == r) my_cand = m;
        if (((m >> 3) & 63) == lane) {
            alive &= ~(1ull << (((m >> 9) << 3) | (m & 7)));
            k1 = k2; k2 = 0;
            if (k1 == 0) {                  // register rescan with alive mask
#pragma unroll
                for (int p = 0; p < 8; ++p)
#pragma unroll
                    for (int jj = 0; jj < 8; ++jj) {
                        unsigned key = ((unsigned)s8[p][jj] << 12) |
                                       (unsigned)((lane + (p << 6)) * 8 + jj);
                        if (!((alive >> (p * 8 + jj)) & 1)) key = 0;
                        if (key > k2) { if (key > k1) { k2 = k1; k1 = key; } else k2 = key; }
                    }
            }
        }
    }

    // exact fp32 rescore: lane = (candidate j, c-half h)
    sxn[w][lane] = xt[((size_t)b * N + n) * 64 + lane];
    const float* xt_ = xt + (size_t)b * N * 64;
    const int jc = lane & 31, h = lane >> 5;
    const int mj = __shfl(my_cand, jc);
    const float* xr = xt_ + (size_t)mj * 64 + h * 32;
    float acc = 0.f;
#pragma unroll
    for (int q8 = 0; q8 < 8; ++q8) {
        float4 g4 = *(const float4*)&xr[q8 * 4];
        float4 xn4 = *(const float4*)&sxn[w][h * 32 + q8 * 4];
        acc += g4.x * xn4.x + g4.y * xn4.y + g4.z * xn4.z + g4.w * xn4.w;
    }
    acc += __shfl_xor(acc, 32);
    float ex = 2.f * acc - xx[(size_t)b * N + mj];
    unsigned fu = __builtin_bit_cast(unsigned, ex);
    unsigned sf = fu ^ (unsigned)(((int)fu >> 31) | 0x80000000);

    // exact top-k SET among KC candidates; winner r kept in lane r's fin_m
    int fin_m = 0;
#pragma unroll 1
    for (int r = 0; r < k; ++r) {
        unsigned bs = sf;
#pragma unroll
        for (int off = 1; off < 64; off <<= 1) {
            unsigned ov = __shfl_xor(bs, off);
            bs = bs > ov ? bs : ov;
        }
        unsigned long long bal = __ballot(sf == bs);
        int L = __ffsll(bal) - 1;
        int m_win = __shfl(mj, L);
        if (lane == r) fin_m = m_win;
        if (mj == m_win) sf = 0;            // clears both h-copies of the candidate
    }

    // fused BN stats gather: lane = o
    const __half* ub = u + (size_t)b * N * O;
    size_t rowb = (size_t)b * N + n;
    float vv = __half2float(v[rowb * O + lane]);
    float gmax = -FLT_MAX, gmin = FLT_MAX, gs = 0.f, gs2 = 0.f;
#pragma unroll
    for (int kk = 0; kk < KMAX; ++kk) {
        int mk = __shfl(fin_m, kk);         // lanes >= k hold 0 (valid address)
        float g = __half2float(ub[(size_t)mk * O + lane]);
        if (kk < k) {
            gs += g; gs2 += g * g;
            gmax = fmaxf(gmax, g); gmin = fminf(gmin, g);
        }
    }
    float fk = (float)k;
    float s  = gs + fk * vv;
    float s2 = gs2 + 2.f * vv * gs + fk * vv * vv;
    ext[rowb * O + lane] = __halves2half2(__float2half(gmax + vv), __float2half(gmin + vv));
    rsum[t] = s; rsum2[t] = s2;
    __syncthreads();
    if (t < 64) {
        float a  = rsum[t] + rsum[t + 64] + rsum[t + 128] + rsum[t + 192];
        float a2 = rsum2[t] + rsum2[t + 64] + rsum2[t + 128] + rsum2[t + 192];
        atomicAdd(&stats[t], a);
        atomicAdd(&stats[64 + t], a2);
    }
}

// ---------- finalize BN affine ----------
__global__ void ec_final(const float* __restrict__ stats,
                         const float* __restrict__ gamma,
                         const float* __restrict__ beta,
                         const int* __restrict__ kptr,
                         float* __restrict__ scsh) {
    int o = threadIdx.x;                   // 64
    int k = *kptr;
    float M = (float)B * (float)N * (float)k;
    float mean = stats[o] / M;
    float var = stats[64 + o] / M - mean * mean;
    var = fmaxf(var, 0.f);
    float sc = gamma[o] * rsqrtf(var + 1e-5f);
    float sh = beta[o] - mean * sc;
    scsh[o] = sc;
    scsh[64 + o] = sh;
}

// ---------- output: pick extreme by sc sign, BN + leaky, transpose ----------
__global__ __launch_bounds__(256) void ec_out(const __half2* __restrict__ ext,
                                              const float* __restrict__ scsh,
                                              float* __restrict__ out) {
    __shared__ float res[64][65];
    const int blk = blockIdx.x;            // B*N/64
    const int b = blk >> 6;
    const int n0 = (blk & 63) << 6;
    const int t = threadIdx.x;
    {
        const int o = t & 63, ni = t >> 6;
        float sc = scsh[o], sh = scsh[64 + o];
#pragma unroll 1
        for (int p = 0; p < 16; ++p) {
            int nl = ni * 16 + p;
            size_t a = ((size_t)b * N + n0 + nl) * O + o;
            __half2 e = ext[a];
            float y = (sc >= 0.f) ? __low2float(e) : __high2float(e);
            float z = sc * y + sh;
            res[nl][o] = (z >= 0.f) ? z : 0.2f * z;
        }
    }
    __syncthreads();
    {
        const int j = t & 63, oi = t >> 6;
#pragma unroll 1
        for (int p = 0; p < 16; ++p) {
            int o2 = oi * 16 + p;
            out[(size_t)b * O * N + (size_t)o2 * N + n0 + j] = res[j][o2];
        }
    }
}

extern "C" void kernel_launch(void* const* d_in, const int* in_sizes, int n_in,
                              void* d_out, int out_size, void* d_ws, size_t ws_size,
                              hipStream_t stream) {
    const float* x     = (const float*)d_in[0];
    const float* W     = (const float*)d_in[1];
    const float* gamma = (const float*)d_in[2];
    const float* beta  = (const float*)d_in[3];
    const int*   kptr  = (const int*)d_in[4];
    float* out = (float*)d_out;

    char* ws = (char*)d_ws;
    u16*    dbf  = (u16*)ws;    ws += (size_t)2 * N * N * 2;       // 64 MB, 2 batches
    float*  xx   = (float*)ws;  ws += (size_t)B * N * 4;
    float*  xt   = (float*)ws;  ws += (size_t)B * N * C * 4;       // 8 MB
    u16*    xtb  = (u16*)ws;    ws += (size_t)B * N * C * 2;       // 4 MB
    __half* u_t  = (__half*)ws; ws += (size_t)B * N * O * 2;       // 4 MB
    __half* v_t  = (__half*)ws; ws += (size_t)B * N * O * 2;       // 4 MB
    __half2* ext = (__half2*)ws; ws += (size_t)B * N * O * 4;      // 8 MB
    float* stats = (float*)ws;  ws += 512;
    float* scsh  = (float*)ws;

    hipMemsetAsync(stats, 0, 512, stream);
    ec_prep<<<B * N / 64, 256, 0, stream>>>(x, W, xx, xt, xtb, u_t, v_t);
    for (int pb = 0; pb < 4; ++pb) {
        ec_gemm<<<dim3(N / 128, N / 128, 2), 256, 0, stream>>>(xtb, xx, dbf, 2 * pb);
        ec_topk<<<dim3(N / 4, 2), 256, 0, stream>>>(dbf, xt, xx, u_t, v_t, kptr, ext, stats, 2 * pb);
    }
    ec_final<<<1, 64, 0, stream>>>(stats, gamma, beta, kptr, scsh);
    ec_out<<<B * N / 64, 256, 0, stream>>>(ext, scsh, out);
}

// Round 7
// 367.691 us; speedup vs baseline: 1.4104x; 1.4104x over previous
//
#include <hip/hip_runtime.h>
#include <hip/hip_fp16.h>
#include <float.h>

#define B 8
#define C 64
#define N 4096
#define O 64
#define KMAX 32

typedef unsigned short u16;
typedef unsigned int u32;
typedef unsigned long long u64;
typedef __attribute__((ext_vector_type(8))) u16 u16x8;
typedef __attribute__((ext_vector_type(8))) short bf16x8;
typedef __attribute__((ext_vector_type(4))) float f32x4;

__device__ __forceinline__ u16 f2bf(float f) {
    unsigned u = __builtin_bit_cast(unsigned, f);
    unsigned r = (u + 0x7FFFu + ((u >> 16) & 1)) >> 16;   // RTNE
    return (u16)r;
}

// ---------- fused prep: xt fp32, xtb bf16, xx, u/v fp16 ----------
__global__ __launch_bounds__(256) void ec_prep(const float* __restrict__ x,
                                               const float* __restrict__ W,
                                               float* __restrict__ xx,
                                               float* __restrict__ xt,
                                               u16* __restrict__ xtb,
                                               __half* __restrict__ u,
                                               __half* __restrict__ v) {
    __shared__ float xs[64][65];
    __shared__ float W1[C][64];
    __shared__ float Wd[C][64];
    __shared__ float rs[4][64];
    const int blk = blockIdx.x;            // B*N/64 = 512
    const int b = blk >> 6;
    const int n0 = (blk & 63) << 6;
    const int t = threadIdx.x;
#pragma unroll
    for (int p = 0; p < 16; ++p) {
        int q = t + 256 * p; int c = q >> 6, j = q & 63;
        xs[c][j] = x[(size_t)b * C * N + (size_t)c * N + n0 + j];
    }
#pragma unroll
    for (int p = 0; p < 16; ++p) {
        int q = t + 256 * p; int c = q >> 6, o = q & 63;
        float w1 = W[o * 128 + c];
        float w2 = W[o * 128 + 64 + c];
        W1[c][o] = w1; Wd[c][o] = w2 - w1;
    }
    __syncthreads();
    {
        const int j = t >> 2, g = t & 3;
        float vals[16]; float ss = 0.f;
#pragma unroll
        for (int i = 0; i < 16; ++i) { float f = xs[g * 16 + i][j]; vals[i] = f; ss += f * f; }
        rs[g][j] = ss;
        size_t rowb = ((size_t)b * N + n0 + j) * 64 + g * 16;
#pragma unroll
        for (int i = 0; i < 4; ++i) {
            float4 v4 = { vals[4 * i], vals[4 * i + 1], vals[4 * i + 2], vals[4 * i + 3] };
            *(float4*)&xt[rowb + 4 * i] = v4;
        }
        u16x8 h0, h1;
#pragma unroll
        for (int i = 0; i < 8; ++i) { h0[i] = f2bf(vals[i]); h1[i] = f2bf(vals[8 + i]); }
        *(u16x8*)&xtb[rowb] = h0;
        *(u16x8*)&xtb[rowb + 8] = h1;
    }
    {
        const int o = t & 63, ji = t >> 6;
#pragma unroll 1
        for (int p = 0; p < 16; ++p) {
            int j = ji + 4 * p;
            float su = 0.f, sv = 0.f;
#pragma unroll
            for (int c = 0; c < C; ++c) {
                float xv = xs[c][j];
                su += xv * W1[c][o];
                sv += xv * Wd[c][o];
            }
            size_t base = ((size_t)b * N + n0 + j) * O + o;
            u[base] = __float2half(su);
            v[base] = __float2half(sv);
        }
    }
    __syncthreads();
    if (t < 64) xx[(size_t)b * N + t + n0] = rs[0][t] + rs[1][t] + rs[2][t] + rs[3][t];
}

// ---------- MFMA distance + fused per-(row,64-col-chunk) top-8 ----------
// cand[((b*N+row)*64 + chunk)*8 + s] : packed u32 = (key16<<12)|(4095-m)
__global__ __launch_bounds__(256) void ec_gemm(const u16* __restrict__ xtb,
                                               const float* __restrict__ xx,
                                               u32* __restrict__ cand) {
    __shared__ u16 lds[18432 + 8];
    const int t = threadIdx.x;
    const int m0 = blockIdx.x * 128, n0 = blockIdx.y * 128;
    const int b = blockIdx.z;
    const u16* xa = xtb + (size_t)b * N * 64;
#pragma unroll
    for (int p = 0; p < 4; ++p) {
        int q = t + 256 * p;
        int row = q >> 3, ch = q & 7;
        int by = (row * 128 + ch * 16) ^ ((row & 7) << 4);
        *(u16x8*)((char*)lds + by) = *(const u16x8*)&xa[(size_t)(n0 + row) * 64 + ch * 8];
        *(u16x8*)((char*)lds + 16384 + by) = *(const u16x8*)&xa[(size_t)(m0 + row) * 64 + ch * 8];
    }
    __syncthreads();
    const int w = t >> 6, lane = t & 63;
    const int wr = w >> 1, wc = w & 1;
    const int fr = lane & 15, fg = lane >> 4;
    f32x4 acc[4][4] = {};
#pragma unroll
    for (int ks = 0; ks < 2; ++ks) {
        bf16x8 af[4], bg[4];
#pragma unroll
        for (int fi = 0; fi < 4; ++fi) {
            int rowA = 64 * wr + 16 * fi + fr;
            int byA = (rowA * 128 + ks * 64 + fg * 16) ^ ((rowA & 7) << 4);
            af[fi] = *(const bf16x8*)((const char*)lds + byA);
            int rowB = 64 * wc + 16 * fi + fr;
            int byB = (rowB * 128 + ks * 64 + fg * 16) ^ ((rowB & 7) << 4);
            bg[fi] = *(const bf16x8*)((const char*)lds + 16384 + byB);
        }
#pragma unroll
        for (int fi = 0; fi < 4; ++fi)
#pragma unroll
            for (int fj = 0; fj < 4; ++fj)
                acc[fi][fj] = __builtin_amdgcn_mfma_f32_16x16x32_bf16(af[fi], bg[fj], acc[fi][fj], 0, 0, 0);
    }
    float xm[4];
#pragma unroll
    for (int fj = 0; fj < 4; ++fj) xm[fj] = xx[(size_t)b * N + m0 + 64 * wc + 16 * fj + fr];
    __syncthreads();                        // staging LDS dead; reuse for epilogue
    u16* ep = lds + w * 4608;               // 64 rows x stride 72 u16 (144 B, 16B-aligned)
#pragma unroll
    for (int fi = 0; fi < 4; ++fi)
#pragma unroll
        for (int fj = 0; fj < 4; ++fj)
#pragma unroll
            for (int r = 0; r < 4; ++r) {
                float dv = 2.f * acc[fi][fj][r] - xm[fj];
                unsigned fu = __builtin_bit_cast(unsigned, dv);
                unsigned sf = fu ^ (unsigned)(((int)fu >> 31) | 0x80000000);
                int row = 16 * fi + fg * 4 + r, col = 16 * fj + fr;
                ep[row * 72 + col] = (u16)((sf + 0x8000u) >> 16);   // rounded sortable key
            }
    __syncthreads();
    // per-lane: row = lane within quadrant; sorted-desc top-8 over 64 cols
    const u16* myrow = lds + w * 4608 + lane * 72;
    const int mbase = m0 + (wc << 6);
    u32 t0 = 0, t1 = 0, t2 = 0, t3 = 0, t4 = 0, t5 = 0, t6 = 0, t7 = 0;
#pragma unroll
    for (int p = 0; p < 8; ++p) {
        u16x8 q = *(const u16x8*)&myrow[p * 8];
#pragma unroll
        for (int jj = 0; jj < 8; ++jj) {
            u32 pk = ((u32)q[jj] << 12) | (u32)(4095 - (mbase + p * 8 + jj));
            t7 = max(t7, min(t6, pk));
            t6 = max(t6, min(t5, pk));
            t5 = max(t5, min(t4, pk));
            t4 = max(t4, min(t3, pk));
            t3 = max(t3, min(t2, pk));
            t2 = max(t2, min(t1, pk));
            t1 = max(t1, min(t0, pk));
            t0 = max(t0, pk);
        }
    }
    const int row_g = n0 + 64 * wr + lane;
    u32* cp = cand + (((size_t)b * N + row_g) * 64 + (size_t)(blockIdx.x * 2 + wc)) * 8;
    uint4 w0 = { t0, t1, t2, t3 }, w1 = { t4, t5, t6, t7 };
    *(uint4*)cp = w0;
    *(uint4*)(cp + 4) = w1;
}

// ---------- bitonic compare-exchange helpers ----------
#define CX2(a, bb, blk) { u32 mn = min(a, bb), mx = max(a, bb); \
                          a = (blk) ? mx : mn; bb = (blk) ? mn : mx; }

// ---------- sel: sort-512 -> top-32 -> exact rescore -> sort-64 -> stats ----------
__global__ __launch_bounds__(256) void ec_sel(const u32* __restrict__ cand,
                                              const float* __restrict__ xt,
                                              const float* __restrict__ xx,
                                              const __half* __restrict__ u,
                                              const __half* __restrict__ v,
                                              const int* __restrict__ kptr,
                                              __half2* __restrict__ ext,
                                              float* __restrict__ stats) {
    __shared__ float sxn[4][64];
    __shared__ int scand[4][32];
    __shared__ float rsum[256], rsum2[256];
    const int t = threadIdx.x, w = t >> 6, lane = t & 63;
    const int b = blockIdx.y;
    const int n = blockIdx.x * 4 + w;
    const int k = *kptr;

    const u32* cp = cand + (((size_t)b * N + n) * 64 + lane) * 8;
    uint4 a0 = *(const uint4*)cp, a1 = *(const uint4*)(cp + 4);
    u32 c0 = a0.x, c1 = a0.y, c2 = a0.z, c3 = a0.w;
    u32 c4 = a1.x, c5 = a1.y, c6 = a1.z, c7 = a1.w;

    // descending bitonic sort of 512 (e = lane*8 + r)
    // s=2
    CX2(c0, c1, true) CX2(c2, c3, false) CX2(c4, c5, true) CX2(c6, c7, false)
    // s=4
    CX2(c0, c2, true) CX2(c1, c3, true) CX2(c4, c6, false) CX2(c5, c7, false)
    CX2(c0, c1, true) CX2(c2, c3, true) CX2(c4, c5, false) CX2(c6, c7, false)
    // s=8
    {
        bool lb = (lane & 1) == 0;
        CX2(c0, c4, lb) CX2(c1, c5, lb) CX2(c2, c6, lb) CX2(c3, c7, lb)
        CX2(c0, c2, lb) CX2(c1, c3, lb) CX2(c4, c6, lb) CX2(c5, c7, lb)
        CX2(c0, c1, lb) CX2(c2, c3, lb) CX2(c4, c5, lb) CX2(c6, c7, lb)
    }
    // s=16..512
#pragma unroll
    for (int ls = 4; ls <= 9; ++ls) {
        const int s = 1 << ls;
        const bool lb = (lane & (s >> 3)) == 0;
#pragma unroll
        for (int dd = s >> 1; dd >= 8; dd >>= 1) {
            const int pl = dd >> 3;
            const bool km0 = ((lane & pl) == 0) == lb;
#define CLX(cr) { u32 pv = __shfl_xor(cr, pl); u32 mn = min(cr, pv), mx = max(cr, pv); \
                  cr = km0 ? mx : mn; }
            CLX(c0) CLX(c1) CLX(c2) CLX(c3) CLX(c4) CLX(c5) CLX(c6) CLX(c7)
#undef CLX
        }
        CX2(c0, c4, lb) CX2(c1, c5, lb) CX2(c2, c6, lb) CX2(c3, c7, lb)
        CX2(c0, c2, lb) CX2(c1, c3, lb) CX2(c4, c6, lb) CX2(c5, c7, lb)
        CX2(c0, c1, lb) CX2(c2, c3, lb) CX2(c4, c5, lb) CX2(c6, c7, lb)
    }
    // top-32 by key live in lanes 0..3 (e = 0..31)
    if (lane < 4) {
        int base = lane * 8;
        scand[w][base + 0] = 4095 - (int)(c0 & 0xFFFu);
        scand[w][base + 1] = 4095 - (int)(c1 & 0xFFFu);
        scand[w][base + 2] = 4095 - (int)(c2 & 0xFFFu);
        scand[w][base + 3] = 4095 - (int)(c3 & 0xFFFu);
        scand[w][base + 4] = 4095 - (int)(c4 & 0xFFFu);
        scand[w][base + 5] = 4095 - (int)(c5 & 0xFFFu);
        scand[w][base + 6] = 4095 - (int)(c6 & 0xFFFu);
        scand[w][base + 7] = 4095 - (int)(c7 & 0xFFFu);
    }
    sxn[w][lane] = xt[((size_t)b * N + n) * 64 + lane];
    __syncthreads();

    // exact fp32 rescore: lane = (candidate jc, c-half h)
    const float* xt_ = xt + (size_t)b * N * 64;
    const int jc = lane & 31, h = lane >> 5;
    const int mj = scand[w][jc];
    const float* xr = xt_ + (size_t)mj * 64 + h * 32;
    float acc = 0.f;
#pragma unroll
    for (int q8 = 0; q8 < 8; ++q8) {
        float4 g4 = *(const float4*)&xr[q8 * 4];
        float4 xn4 = *(const float4*)&sxn[w][h * 32 + q8 * 4];
        acc += g4.x * xn4.x + g4.y * xn4.y + g4.z * xn4.z + g4.w * xn4.w;
    }
    acc += __shfl_xor(acc, 32);
    float ex = 2.f * acc - xx[(size_t)b * N + mj];
    unsigned fu = __builtin_bit_cast(unsigned, ex);
    unsigned sf = fu ^ (unsigned)(((int)fu >> 31) | 0x80000000);
    u64 key = ((u64)sf << 12) | (u64)(4095 - mj);
    if (h) key = 0;                        // kill duplicate copy

    // descending bitonic sort of 64 u64 keys (1/lane)
#pragma unroll
    for (int ls = 1; ls <= 6; ++ls) {
        const int s = 1 << ls;
        const bool lb = (lane & s) == 0;
#pragma unroll
        for (int dd = s >> 1; dd >= 1; dd >>= 1) {
            const bool km = ((lane & dd) == 0) == lb;
            u64 pv = __shfl_xor(key, dd);
            u64 mn = key < pv ? key : pv;
            u64 mx = key < pv ? pv : key;
            key = km ? mx : mn;
        }
    }
    int m_final = 4095 - (int)(key & 0xFFFu);   // lane r = r-th best exact

    // fused BN stats gather: lane = o
    const __half* ub = u + (size_t)b * N * O;
    size_t rowb = (size_t)b * N + n;
    float vv = __half2float(v[rowb * O + lane]);
    float gmax = -FLT_MAX, gmin = FLT_MAX, gs = 0.f, gs2 = 0.f;
#pragma unroll
    for (int kk = 0; kk < KMAX; ++kk) {
        int mk = __shfl(m_final, kk);
        float g = __half2float(ub[(size_t)mk * O + lane]);
        if (kk < k) {
            gs += g; gs2 += g * g;
            gmax = fmaxf(gmax, g); gmin = fminf(gmin, g);
        }
    }
    float fk = (float)k;
    float s  = gs + fk * vv;
    float s2 = gs2 + 2.f * vv * gs + fk * vv * vv;
    ext[rowb * O + lane] = __halves2half2(__float2half(gmax + vv), __float2half(gmin + vv));
    rsum[t] = s; rsum2[t] = s2;
    __syncthreads();
    if (t < 64) {
        float a  = rsum[t] + rsum[t + 64] + rsum[t + 128] + rsum[t + 192];
        float a2 = rsum2[t] + rsum2[t + 64] + rsum2[t + 128] + rsum2[t + 192];
        atomicAdd(&stats[t], a);
        atomicAdd(&stats[64 + t], a2);
    }
}

// ---------- finalize BN affine ----------
__global__ void ec_final(const float* __restrict__ stats,
                         const float* __restrict__ gamma,
                         const float* __restrict__ beta,
                         const int* __restrict__ kptr,
                         float* __restrict__ scsh) {
    int o = threadIdx.x;                   // 64
    int k = *kptr;
    float M = (float)B * (float)N * (float)k;
    float mean = stats[o] / M;
    float var = stats[64 + o] / M - mean * mean;
    var = fmaxf(var, 0.f);
    float sc = gamma[o] * rsqrtf(var + 1e-5f);
    float sh = beta[o] - mean * sc;
    scsh[o] = sc;
    scsh[64 + o] = sh;
}

// ---------- output: pick extreme by sc sign, BN + leaky, transpose ----------
__global__ __launch_bounds__(256) void ec_out(const __half2* __restrict__ ext,
                                              const float* __restrict__ scsh,
                                              float* __restrict__ out) {
    __shared__ float res[64][65];
    const int blk = blockIdx.x;            // B*N/64
    const int b = blk >> 6;
    const int n0 = (blk & 63) << 6;
    const int t = threadIdx.x;
    {
        const int o = t & 63, ni = t >> 6;
        float sc = scsh[o], sh = scsh[64 + o];
#pragma unroll 1
        for (int p = 0; p < 16; ++p) {
            int nl = ni * 16 + p;
            size_t a = ((size_t)b * N + n0 + nl) * O + o;
            __half2 e = ext[a];
            float y = (sc >= 0.f) ? __low2float(e) : __high2float(e);
            float z = sc * y + sh;
            res[nl][o] = (z >= 0.f) ? z : 0.2f * z;
        }
    }
    __syncthreads();
    {
        const int j = t & 63, oi = t >> 6;
#pragma unroll 1
        for (int p = 0; p < 16; ++p) {
            int o2 = oi * 16 + p;
            out[(size_t)b * O * N + (size_t)o2 * N + n0 + j] = res[j][o2];
        }
    }
}

extern "C" void kernel_launch(void* const* d_in, const int* in_sizes, int n_in,
                              void* d_out, int out_size, void* d_ws, size_t ws_size,
                              hipStream_t stream) {
    const float* x     = (const float*)d_in[0];
    const float* W     = (const float*)d_in[1];
    const float* gamma = (const float*)d_in[2];
    const float* beta  = (const float*)d_in[3];
    const int*   kptr  = (const int*)d_in[4];
    float* out = (float*)d_out;

    char* ws = (char*)d_ws;
    u32*    cand = (u32*)ws;    ws += (size_t)B * N * 64 * 8 * 4;  // 64 MB
    float*  xx   = (float*)ws;  ws += (size_t)B * N * 4;
    float*  xt   = (float*)ws;  ws += (size_t)B * N * C * 4;       // 8 MB
    u16*    xtb  = (u16*)ws;    ws += (size_t)B * N * C * 2;       // 4 MB
    __half* u_t  = (__half*)ws; ws += (size_t)B * N * O * 2;       // 4 MB
    __half* v_t  = (__half*)ws; ws += (size_t)B * N * O * 2;       // 4 MB
    __half2* ext = (__half2*)ws; ws += (size_t)B * N * O * 4;      // 8 MB
    float* stats = (float*)ws;  ws += 512;
    float* scsh  = (float*)ws;

    hipMemsetAsync(stats, 0, 512, stream);
    ec_prep<<<B * N / 64, 256, 0, stream>>>(x, W, xx, xt, xtb, u_t, v_t);
    ec_gemm<<<dim3(N / 128, N / 128, B), 256, 0, stream>>>(xtb, xx, cand);
    ec_sel<<<dim3(N / 4, B), 256, 0, stream>>>(cand, xt, xx, u_t, v_t, kptr, ext, stats);
    ec_final<<<1, 64, 0, stream>>>(stats, gamma, beta, kptr, scsh);
    ec_out<<<B * N / 64, 256, 0, stream>>>(ext, scsh, out);
}

// Round 8
// 244.987 us; speedup vs baseline: 2.1168x; 1.5009x over previous
//
#include <hip/hip_runtime.h>
#include <hip/hip_fp16.h>
#include <float.h>

#define B 8
#define C 64
#define N 4096
#define O 64
#define KMAX 32
#define NREP 64   // stats replica buffers (atomic contention divider)

typedef unsigned short u16;
typedef unsigned int u32;
typedef unsigned long long u64;
typedef __attribute__((ext_vector_type(8))) u16 u16x8;
typedef __attribute__((ext_vector_type(8))) short bf16x8;
typedef __attribute__((ext_vector_type(4))) float f32x4;

__device__ __forceinline__ u16 f2bf(float f) {
    unsigned u = __builtin_bit_cast(unsigned, f);
    unsigned r = (u + 0x7FFFu + ((u >> 16) & 1)) >> 16;   // RTNE
    return (u16)r;
}

// ---------- fused prep: xt fp32, xtb bf16, xx, u/v fp16 ----------
__global__ __launch_bounds__(256) void ec_prep(const float* __restrict__ x,
                                               const float* __restrict__ W,
                                               float* __restrict__ xx,
                                               float* __restrict__ xt,
                                               u16* __restrict__ xtb,
                                               __half* __restrict__ u,
                                               __half* __restrict__ v) {
    __shared__ float xs[64][65];
    __shared__ float W1[C][64];
    __shared__ float Wd[C][64];
    __shared__ float rs[4][64];
    const int blk = blockIdx.x;            // B*N/64 = 512
    const int b = blk >> 6;
    const int n0 = (blk & 63) << 6;
    const int t = threadIdx.x;
#pragma unroll
    for (int p = 0; p < 16; ++p) {
        int q = t + 256 * p; int c = q >> 6, j = q & 63;
        xs[c][j] = x[(size_t)b * C * N + (size_t)c * N + n0 + j];
    }
#pragma unroll
    for (int p = 0; p < 16; ++p) {
        int q = t + 256 * p; int c = q >> 6, o = q & 63;
        float w1 = W[o * 128 + c];
        float w2 = W[o * 128 + 64 + c];
        W1[c][o] = w1; Wd[c][o] = w2 - w1;
    }
    __syncthreads();
    {
        const int j = t >> 2, g = t & 3;
        float vals[16]; float ss = 0.f;
#pragma unroll
        for (int i = 0; i < 16; ++i) { float f = xs[g * 16 + i][j]; vals[i] = f; ss += f * f; }
        rs[g][j] = ss;
        size_t rowb = ((size_t)b * N + n0 + j) * 64 + g * 16;
#pragma unroll
        for (int i = 0; i < 4; ++i) {
            float4 v4 = { vals[4 * i], vals[4 * i + 1], vals[4 * i + 2], vals[4 * i + 3] };
            *(float4*)&xt[rowb + 4 * i] = v4;
        }
        u16x8 h0, h1;
#pragma unroll
        for (int i = 0; i < 8; ++i) { h0[i] = f2bf(vals[i]); h1[i] = f2bf(vals[8 + i]); }
        *(u16x8*)&xtb[rowb] = h0;
        *(u16x8*)&xtb[rowb + 8] = h1;
    }
    {
        const int o = t & 63, ji = t >> 6;
#pragma unroll 1
        for (int p = 0; p < 16; ++p) {
            int j = ji + 4 * p;
            float su = 0.f, sv = 0.f;
#pragma unroll
            for (int c = 0; c < C; ++c) {
                float xv = xs[c][j];
                su += xv * W1[c][o];
                sv += xv * Wd[c][o];
            }
            size_t base = ((size_t)b * N + n0 + j) * O + o;
            u[base] = __float2half(su);
            v[base] = __float2half(sv);
        }
    }
    __syncthreads();
    if (t < 64) xx[(size_t)b * N + t + n0] = rs[0][t] + rs[1][t] + rs[2][t] + rs[3][t];
}

// ---------- MFMA distance + fused per-(row,64-col-chunk) top-8 ----------
// cand[((b*N+row)*64 + chunk)*8 + s] : packed u32 = (key16<<12)|(4095-m)
__global__ __launch_bounds__(256) void ec_gemm(const u16* __restrict__ xtb,
                                               const float* __restrict__ xx,
                                               u32* __restrict__ cand) {
    __shared__ u16 lds[18432 + 8];
    const int t = threadIdx.x;
    const int m0 = blockIdx.x * 128, n0 = blockIdx.y * 128;
    const int b = blockIdx.z;
    const u16* xa = xtb + (size_t)b * N * 64;
#pragma unroll
    for (int p = 0; p < 4; ++p) {
        int q = t + 256 * p;
        int row = q >> 3, ch = q & 7;
        int by = (row * 128 + ch * 16) ^ ((row & 7) << 4);
        *(u16x8*)((char*)lds + by) = *(const u16x8*)&xa[(size_t)(n0 + row) * 64 + ch * 8];
        *(u16x8*)((char*)lds + 16384 + by) = *(const u16x8*)&xa[(size_t)(m0 + row) * 64 + ch * 8];
    }
    __syncthreads();
    const int w = t >> 6, lane = t & 63;
    const int wr = w >> 1, wc = w & 1;
    const int fr = lane & 15, fg = lane >> 4;
    f32x4 acc[4][4] = {};
#pragma unroll
    for (int ks = 0; ks < 2; ++ks) {
        bf16x8 af[4], bg[4];
#pragma unroll
        for (int fi = 0; fi < 4; ++fi) {
            int rowA = 64 * wr + 16 * fi + fr;
            int byA = (rowA * 128 + ks * 64 + fg * 16) ^ ((rowA & 7) << 4);
            af[fi] = *(const bf16x8*)((const char*)lds + byA);
            int rowB = 64 * wc + 16 * fi + fr;
            int byB = (rowB * 128 + ks * 64 + fg * 16) ^ ((rowB & 7) << 4);
            bg[fi] = *(const bf16x8*)((const char*)lds + 16384 + byB);
        }
#pragma unroll
        for (int fi = 0; fi < 4; ++fi)
#pragma unroll
            for (int fj = 0; fj < 4; ++fj)
                acc[fi][fj] = __builtin_amdgcn_mfma_f32_16x16x32_bf16(af[fi], bg[fj], acc[fi][fj], 0, 0, 0);
    }
    float xm[4];
#pragma unroll
    for (int fj = 0; fj < 4; ++fj) xm[fj] = xx[(size_t)b * N + m0 + 64 * wc + 16 * fj + fr];
    __syncthreads();                        // staging LDS dead; reuse for epilogue
    u16* ep = lds + w * 4608;               // 64 rows x stride 72 u16 (144 B, 16B-aligned)
#pragma unroll
    for (int fi = 0; fi < 4; ++fi)
#pragma unroll
        for (int fj = 0; fj < 4; ++fj)
#pragma unroll
            for (int r = 0; r < 4; ++r) {
                float dv = 2.f * acc[fi][fj][r] - xm[fj];
                unsigned fu = __builtin_bit_cast(unsigned, dv);
                unsigned sf = fu ^ (unsigned)(((int)fu >> 31) | 0x80000000);
                int row = 16 * fi + fg * 4 + r, col = 16 * fj + fr;
                ep[row * 72 + col] = (u16)((sf + 0x8000u) >> 16);   // rounded sortable key
            }
    __syncthreads();
    // per-lane: row = lane within quadrant; sorted-desc top-8 over 64 cols
    const u16* myrow = lds + w * 4608 + lane * 72;
    const int mbase = m0 + (wc << 6);
    u32 t0 = 0, t1 = 0, t2 = 0, t3 = 0, t4 = 0, t5 = 0, t6 = 0, t7 = 0;
#pragma unroll
    for (int p = 0; p < 8; ++p) {
        u16x8 q = *(const u16x8*)&myrow[p * 8];
#pragma unroll
        for (int jj = 0; jj < 8; ++jj) {
            u32 pk = ((u32)q[jj] << 12) | (u32)(4095 - (mbase + p * 8 + jj));
            t7 = max(t7, min(t6, pk));
            t6 = max(t6, min(t5, pk));
            t5 = max(t5, min(t4, pk));
            t4 = max(t4, min(t3, pk));
            t3 = max(t3, min(t2, pk));
            t2 = max(t2, min(t1, pk));
            t1 = max(t1, min(t0, pk));
            t0 = max(t0, pk);
        }
    }
    const int row_g = n0 + 64 * wr + lane;
    u32* cp = cand + (((size_t)b * N + row_g) * 64 + (size_t)(blockIdx.x * 2 + wc)) * 8;
    uint4 w0 = { t0, t1, t2, t3 }, w1 = { t4, t5, t6, t7 };
    *(uint4*)cp = w0;
    *(uint4*)(cp + 4) = w1;
}

// ---------- bitonic compare-exchange helpers ----------
#define CX2(a, bb, blk) { u32 mn = min(a, bb), mx = max(a, bb); \
                          a = (blk) ? mx : mn; bb = (blk) ? mn : mx; }

// ---------- sel: sort-512 -> top-32 -> exact rescore -> sort-64 -> stats ----------
__global__ __launch_bounds__(256) void ec_sel(const u32* __restrict__ cand,
                                              const float* __restrict__ xt,
                                              const float* __restrict__ xx,
                                              const __half* __restrict__ u,
                                              const __half* __restrict__ v,
                                              const int* __restrict__ kptr,
                                              __half2* __restrict__ ext,
                                              float* __restrict__ statsR) {
    __shared__ float sxn[4][64];
    __shared__ int scand[4][32];
    __shared__ float rsum[256], rsum2[256];
    const int t = threadIdx.x, w = t >> 6, lane = t & 63;
    const int b = blockIdx.y;
    const int n = blockIdx.x * 4 + w;
    const int k = *kptr;

    const u32* cp = cand + (((size_t)b * N + n) * 64 + lane) * 8;
    uint4 a0 = *(const uint4*)cp, a1 = *(const uint4*)(cp + 4);
    u32 c0 = a0.x, c1 = a0.y, c2 = a0.z, c3 = a0.w;
    u32 c4 = a1.x, c5 = a1.y, c6 = a1.z, c7 = a1.w;

    // descending bitonic sort of 512 (e = lane*8 + r)
    // s=2
    CX2(c0, c1, true) CX2(c2, c3, false) CX2(c4, c5, true) CX2(c6, c7, false)
    // s=4
    CX2(c0, c2, true) CX2(c1, c3, true) CX2(c4, c6, false) CX2(c5, c7, false)
    CX2(c0, c1, true) CX2(c2, c3, true) CX2(c4, c5, false) CX2(c6, c7, false)
    // s=8
    {
        bool lb = (lane & 1) == 0;
        CX2(c0, c4, lb) CX2(c1, c5, lb) CX2(c2, c6, lb) CX2(c3, c7, lb)
        CX2(c0, c2, lb) CX2(c1, c3, lb) CX2(c4, c6, lb) CX2(c5, c7, lb)
        CX2(c0, c1, lb) CX2(c2, c3, lb) CX2(c4, c5, lb) CX2(c6, c7, lb)
    }
    // s=16..512
#pragma unroll
    for (int ls = 4; ls <= 9; ++ls) {
        const int s = 1 << ls;
        const bool lb = (lane & (s >> 3)) == 0;
#pragma unroll
        for (int dd = s >> 1; dd >= 8; dd >>= 1) {
            const int pl = dd >> 3;
            const bool km0 = ((lane & pl) == 0) == lb;
#define CLX(cr) { u32 pv = __shfl_xor(cr, pl); u32 mn = min(cr, pv), mx = max(cr, pv); \
                  cr = km0 ? mx : mn; }
            CLX(c0) CLX(c1) CLX(c2) CLX(c3) CLX(c4) CLX(c5) CLX(c6) CLX(c7)
#undef CLX
        }
        CX2(c0, c4, lb) CX2(c1, c5, lb) CX2(c2, c6, lb) CX2(c3, c7, lb)
        CX2(c0, c2, lb) CX2(c1, c3, lb) CX2(c4, c6, lb) CX2(c5, c7, lb)
        CX2(c0, c1, lb) CX2(c2, c3, lb) CX2(c4, c5, lb) CX2(c6, c7, lb)
    }
    // top-32 by key live in lanes 0..3 (e = 0..31)
    if (lane < 4) {
        int base = lane * 8;
        scand[w][base + 0] = 4095 - (int)(c0 & 0xFFFu);
        scand[w][base + 1] = 4095 - (int)(c1 & 0xFFFu);
        scand[w][base + 2] = 4095 - (int)(c2 & 0xFFFu);
        scand[w][base + 3] = 4095 - (int)(c3 & 0xFFFu);
        scand[w][base + 4] = 4095 - (int)(c4 & 0xFFFu);
        scand[w][base + 5] = 4095 - (int)(c5 & 0xFFFu);
        scand[w][base + 6] = 4095 - (int)(c6 & 0xFFFu);
        scand[w][base + 7] = 4095 - (int)(c7 & 0xFFFu);
    }
    sxn[w][lane] = xt[((size_t)b * N + n) * 64 + lane];
    __syncthreads();

    // exact fp32 rescore: lane = (candidate jc, c-half h)
    const float* xt_ = xt + (size_t)b * N * 64;
    const int jc = lane & 31, h = lane >> 5;
    const int mj = scand[w][jc];
    const float* xr = xt_ + (size_t)mj * 64 + h * 32;
    float acc = 0.f;
#pragma unroll
    for (int q8 = 0; q8 < 8; ++q8) {
        float4 g4 = *(const float4*)&xr[q8 * 4];
        float4 xn4 = *(const float4*)&sxn[w][h * 32 + q8 * 4];
        acc += g4.x * xn4.x + g4.y * xn4.y + g4.z * xn4.z + g4.w * xn4.w;
    }
    acc += __shfl_xor(acc, 32);
    float ex = 2.f * acc - xx[(size_t)b * N + mj];
    unsigned fu = __builtin_bit_cast(unsigned, ex);
    unsigned sf = fu ^ (unsigned)(((int)fu >> 31) | 0x80000000);
    u64 key = ((u64)sf << 12) | (u64)(4095 - mj);
    if (h) key = 0;                        // kill duplicate copy

    // descending bitonic sort of 64 u64 keys (1/lane)
#pragma unroll
    for (int ls = 1; ls <= 6; ++ls) {
        const int s = 1 << ls;
        const bool lb = (lane & s) == 0;
#pragma unroll
        for (int dd = s >> 1; dd >= 1; dd >>= 1) {
            const bool km = ((lane & dd) == 0) == lb;
            u64 pv = __shfl_xor(key, dd);
            u64 mn = key < pv ? key : pv;
            u64 mx = key < pv ? pv : key;
            key = km ? mx : mn;
        }
    }
    int m_final = 4095 - (int)(key & 0xFFFu);   // lane r = r-th best exact

    // fused BN stats gather: lane = o. Hoist shfls, then 32 independent loads.
    const __half* ub = u + (size_t)b * N * O;
    size_t rowb = (size_t)b * N + n;
    float vv = __half2float(v[rowb * O + lane]);
    int mks[KMAX];
#pragma unroll
    for (int kk = 0; kk < KMAX; ++kk) mks[kk] = __shfl(m_final, kk);
    float g[KMAX];
#pragma unroll
    for (int kk = 0; kk < KMAX; ++kk)
        g[kk] = __half2float(ub[(size_t)mks[kk] * O + lane]);
    float gmax = -FLT_MAX, gmin = FLT_MAX, gs = 0.f, gs2 = 0.f;
#pragma unroll
    for (int kk = 0; kk < KMAX; ++kk) {
        if (kk < k) {
            gs += g[kk]; gs2 += g[kk] * g[kk];
            gmax = fmaxf(gmax, g[kk]); gmin = fminf(gmin, g[kk]);
        }
    }
    float fk = (float)k;
    float s  = gs + fk * vv;
    float s2 = gs2 + 2.f * vv * gs + fk * vv * vv;
    ext[rowb * O + lane] = __halves2half2(__float2half(gmax + vv), __float2half(gmin + vv));
    rsum[t] = s; rsum2[t] = s2;
    __syncthreads();
    if (t < 64) {
        float a  = rsum[t] + rsum[t + 64] + rsum[t + 128] + rsum[t + 192];
        float a2 = rsum2[t] + rsum2[t + 64] + rsum2[t + 128] + rsum2[t + 192];
        float* sr = statsR + (size_t)(blockIdx.x & (NREP - 1)) * 128;
        atomicAdd(&sr[t], a);
        atomicAdd(&sr[64 + t], a2);
    }
}

// ---------- finalize BN affine (reduce NREP replicas) ----------
__global__ void ec_final(const float* __restrict__ statsR,
                         const float* __restrict__ gamma,
                         const float* __restrict__ beta,
                         const int* __restrict__ kptr,
                         float* __restrict__ scsh) {
    int o = threadIdx.x;                   // 64
    int k = *kptr;
    float s = 0.f, s2 = 0.f;
    for (int r = 0; r < NREP; ++r) {
        s  += statsR[r * 128 + o];
        s2 += statsR[r * 128 + 64 + o];
    }
    float M = (float)B * (float)N * (float)k;
    float mean = s / M;
    float var = s2 / M - mean * mean;
    var = fmaxf(var, 0.f);
    float sc = gamma[o] * rsqrtf(var + 1e-5f);
    float sh = beta[o] - mean * sc;
    scsh[o] = sc;
    scsh[64 + o] = sh;
}

// ---------- output: pick extreme by sc sign, BN + leaky, transpose ----------
__global__ __launch_bounds__(256) void ec_out(const __half2* __restrict__ ext,
                                              const float* __restrict__ scsh,
                                              float* __restrict__ out) {
    __shared__ float res[64][65];
    const int blk = blockIdx.x;            // B*N/64
    const int b = blk >> 6;
    const int n0 = (blk & 63) << 6;
    const int t = threadIdx.x;
    {
        const int o = t & 63, ni = t >> 6;
        float sc = scsh[o], sh = scsh[64 + o];
#pragma unroll 1
        for (int p = 0; p < 16; ++p) {
            int nl = ni * 16 + p;
            size_t a = ((size_t)b * N + n0 + nl) * O + o;
            __half2 e = ext[a];
            float y = (sc >= 0.f) ? __low2float(e) : __high2float(e);
            float z = sc * y + sh;
            res[nl][o] = (z >= 0.f) ? z : 0.2f * z;
        }
    }
    __syncthreads();
    {
        const int j = t & 63, oi = t >> 6;
#pragma unroll 1
        for (int p = 0; p < 16; ++p) {
            int o2 = oi * 16 + p;
            out[(size_t)b * O * N + (size_t)o2 * N + n0 + j] = res[j][o2];
        }
    }
}

extern "C" void kernel_launch(void* const* d_in, const int* in_sizes, int n_in,
                              void* d_out, int out_size, void* d_ws, size_t ws_size,
                              hipStream_t stream) {
    const float* x     = (const float*)d_in[0];
    const float* W     = (const float*)d_in[1];
    const float* gamma = (const float*)d_in[2];
    const float* beta  = (const float*)d_in[3];
    const int*   kptr  = (const int*)d_in[4];
    float* out = (float*)d_out;

    char* ws = (char*)d_ws;
    u32*    cand = (u32*)ws;    ws += (size_t)B * N * 64 * 8 * 4;  // 64 MB
    float*  xx   = (float*)ws;  ws += (size_t)B * N * 4;
    float*  xt   = (float*)ws;  ws += (size_t)B * N * C * 4;       // 8 MB
    u16*    xtb  = (u16*)ws;    ws += (size_t)B * N * C * 2;       // 4 MB
    __half* u_t  = (__half*)ws; ws += (size_t)B * N * O * 2;       // 4 MB
    __half* v_t  = (__half*)ws; ws += (size_t)B * N * O * 2;       // 4 MB
    __half2* ext = (__half2*)ws; ws += (size_t)B * N * O * 4;      // 8 MB
    float* statsR = (float*)ws; ws += (size_t)NREP * 128 * 4;      // 32 KB
    float* scsh  = (float*)ws;

    hipMemsetAsync(statsR, 0, NREP * 128 * 4, stream);
    ec_prep<<<B * N / 64, 256, 0, stream>>>(x, W, xx, xt, xtb, u_t, v_t);
    ec_gemm<<<dim3(N / 128, N / 128, B), 256, 0, stream>>>(xtb, xx, cand);
    ec_sel<<<dim3(N / 4, B), 256, 0, stream>>>(cand, xt, xx, u_t, v_t, kptr, ext, statsR);
    ec_final<<<1, 64, 0, stream>>>(statsR, gamma, beta, kptr, scsh);
    ec_out<<<B * N / 64, 256, 0, stream>>>(ext, scsh, out);
}

// Round 9
// 223.982 us; speedup vs baseline: 2.3153x; 1.0938x over previous
//
#include <hip/hip_runtime.h>
#include <hip/hip_fp16.h>
#include <float.h>

#define B 8
#define C 64
#define N 4096
#define O 64
#define KMAX 32
#define NREP 64   // stats replica buffers (atomic contention divider)

typedef unsigned short u16;
typedef unsigned int u32;
typedef unsigned long long u64;
typedef __attribute__((ext_vector_type(8))) u16 u16x8;
typedef __attribute__((ext_vector_type(8))) short bf16x8;
typedef __attribute__((ext_vector_type(4))) float f32x4;

__device__ __forceinline__ u16 f2bf(float f) {
    unsigned u = __builtin_bit_cast(unsigned, f);
    unsigned r = (u + 0x7FFFu + ((u >> 16) & 1)) >> 16;   // RTNE
    return (u16)r;
}

// ---------- fused prep: xt fp32, xtb bf16, xx, u/v fp16 ----------
__global__ __launch_bounds__(256) void ec_prep(const float* __restrict__ x,
                                               const float* __restrict__ W,
                                               float* __restrict__ xx,
                                               float* __restrict__ xt,
                                               u16* __restrict__ xtb,
                                               __half* __restrict__ u,
                                               __half* __restrict__ v) {
    __shared__ float xs[64][65];
    __shared__ float W1[C][64];
    __shared__ float Wd[C][64];
    __shared__ float rs[4][64];
    const int blk = blockIdx.x;            // B*N/64 = 512
    const int b = blk >> 6;
    const int n0 = (blk & 63) << 6;
    const int t = threadIdx.x;
#pragma unroll
    for (int p = 0; p < 16; ++p) {
        int q = t + 256 * p; int c = q >> 6, j = q & 63;
        xs[c][j] = x[(size_t)b * C * N + (size_t)c * N + n0 + j];
    }
#pragma unroll
    for (int p = 0; p < 16; ++p) {
        int q = t + 256 * p; int c = q >> 6, o = q & 63;
        float w1 = W[o * 128 + c];
        float w2 = W[o * 128 + 64 + c];
        W1[c][o] = w1; Wd[c][o] = w2 - w1;
    }
    __syncthreads();
    {
        const int j = t >> 2, g = t & 3;
        float vals[16]; float ss = 0.f;
#pragma unroll
        for (int i = 0; i < 16; ++i) { float f = xs[g * 16 + i][j]; vals[i] = f; ss += f * f; }
        rs[g][j] = ss;
        size_t rowb = ((size_t)b * N + n0 + j) * 64 + g * 16;
#pragma unroll
        for (int i = 0; i < 4; ++i) {
            float4 v4 = { vals[4 * i], vals[4 * i + 1], vals[4 * i + 2], vals[4 * i + 3] };
            *(float4*)&xt[rowb + 4 * i] = v4;
        }
        u16x8 h0, h1;
#pragma unroll
        for (int i = 0; i < 8; ++i) { h0[i] = f2bf(vals[i]); h1[i] = f2bf(vals[8 + i]); }
        *(u16x8*)&xtb[rowb] = h0;
        *(u16x8*)&xtb[rowb + 8] = h1;
    }
    {
        const int o = t & 63, ji = t >> 6;
#pragma unroll 1
        for (int p = 0; p < 16; ++p) {
            int j = ji + 4 * p;
            float su = 0.f, sv = 0.f;
#pragma unroll
            for (int c = 0; c < C; ++c) {
                float xv = xs[c][j];
                su += xv * W1[c][o];
                sv += xv * Wd[c][o];
            }
            size_t base = ((size_t)b * N + n0 + j) * O + o;
            u[base] = __float2half(su);
            v[base] = __float2half(sv);
        }
    }
    __syncthreads();
    if (t < 64) xx[(size_t)b * N + t + n0] = rs[0][t] + rs[1][t] + rs[2][t] + rs[3][t];
}

// ---------- MFMA distance + fused per-(row,64-col-chunk) top-8 ----------
// cand[((b*N+row)*64 + chunk)*8 + s] : packed u32 = (key16<<12)|(4095-m)
__global__ __launch_bounds__(256) void ec_gemm(const u16* __restrict__ xtb,
                                               const float* __restrict__ xx,
                                               u32* __restrict__ cand) {
    __shared__ u16 lds[18432 + 8];
    const int t = threadIdx.x;
    const int m0 = blockIdx.x * 128, n0 = blockIdx.y * 128;
    const int b = blockIdx.z;
    const u16* xa = xtb + (size_t)b * N * 64;
#pragma unroll
    for (int p = 0; p < 4; ++p) {
        int q = t + 256 * p;
        int row = q >> 3, ch = q & 7;
        int by = (row * 128 + ch * 16) ^ ((row & 7) << 4);
        *(u16x8*)((char*)lds + by) = *(const u16x8*)&xa[(size_t)(n0 + row) * 64 + ch * 8];
        *(u16x8*)((char*)lds + 16384 + by) = *(const u16x8*)&xa[(size_t)(m0 + row) * 64 + ch * 8];
    }
    __syncthreads();
    const int w = t >> 6, lane = t & 63;
    const int wr = w >> 1, wc = w & 1;
    const int fr = lane & 15, fg = lane >> 4;
    f32x4 acc[4][4] = {};
#pragma unroll
    for (int ks = 0; ks < 2; ++ks) {
        bf16x8 af[4], bg[4];
#pragma unroll
        for (int fi = 0; fi < 4; ++fi) {
            int rowA = 64 * wr + 16 * fi + fr;
            int byA = (rowA * 128 + ks * 64 + fg * 16) ^ ((rowA & 7) << 4);
            af[fi] = *(const bf16x8*)((const char*)lds + byA);
            int rowB = 64 * wc + 16 * fi + fr;
            int byB = (rowB * 128 + ks * 64 + fg * 16) ^ ((rowB & 7) << 4);
            bg[fi] = *(const bf16x8*)((const char*)lds + 16384 + byB);
        }
#pragma unroll
        for (int fi = 0; fi < 4; ++fi)
#pragma unroll
            for (int fj = 0; fj < 4; ++fj)
                acc[fi][fj] = __builtin_amdgcn_mfma_f32_16x16x32_bf16(af[fi], bg[fj], acc[fi][fj], 0, 0, 0);
    }
    float xm[4];
#pragma unroll
    for (int fj = 0; fj < 4; ++fj) xm[fj] = xx[(size_t)b * N + m0 + 64 * wc + 16 * fj + fr];
    __syncthreads();                        // staging LDS dead; reuse for epilogue
    u16* ep = lds + w * 4608;               // 64 rows x stride 72 u16 (144 B, 16B-aligned)
#pragma unroll
    for (int fi = 0; fi < 4; ++fi)
#pragma unroll
        for (int fj = 0; fj < 4; ++fj)
#pragma unroll
            for (int r = 0; r < 4; ++r) {
                float dv = 2.f * acc[fi][fj][r] - xm[fj];
                unsigned fu = __builtin_bit_cast(unsigned, dv);
                unsigned sf = fu ^ (unsigned)(((int)fu >> 31) | 0x80000000);
                int row = 16 * fi + fg * 4 + r, col = 16 * fj + fr;
                ep[row * 72 + col] = (u16)((sf + 0x8000u) >> 16);   // rounded sortable key
            }
    __syncthreads();
    // per-lane: row = lane within quadrant; sorted-desc top-8 over 64 cols
    const u16* myrow = lds + w * 4608 + lane * 72;
    const int mbase = m0 + (wc << 6);
    u32 t0 = 0, t1 = 0, t2 = 0, t3 = 0, t4 = 0, t5 = 0, t6 = 0, t7 = 0;
#pragma unroll
    for (int p = 0; p < 8; ++p) {
        u16x8 q = *(const u16x8*)&myrow[p * 8];
#pragma unroll
        for (int jj = 0; jj < 8; ++jj) {
            u32 pk = ((u32)q[jj] << 12) | (u32)(4095 - (mbase + p * 8 + jj));
            t7 = max(t7, min(t6, pk));
            t6 = max(t6, min(t5, pk));
            t5 = max(t5, min(t4, pk));
            t4 = max(t4, min(t3, pk));
            t3 = max(t3, min(t2, pk));
            t2 = max(t2, min(t1, pk));
            t1 = max(t1, min(t0, pk));
            t0 = max(t0, pk);
        }
    }
    const int row_g = n0 + 64 * wr + lane;
    u32* cp = cand + (((size_t)b * N + row_g) * 64 + (size_t)(blockIdx.x * 2 + wc)) * 8;
    uint4 w0 = { t0, t1, t2, t3 }, w1 = { t4, t5, t6, t7 };
    *(uint4*)cp = w0;
    *(uint4*)(cp + 4) = w1;
}

// ---------- merge-tree helpers (in-register, 8 keys/lane) ----------
#define CXD(i, j) { u32 mn_ = min(c[i], c[j]); c[i] = max(c[i], c[j]); c[j] = mn_; }
#define CLEAN8() { CXD(0,4) CXD(1,5) CXD(2,6) CXD(3,7) \
                   CXD(0,2) CXD(1,3) CXD(4,6) CXD(5,7) \
                   CXD(0,1) CXD(2,3) CXD(4,5) CXD(6,7) }
// distributed bitonic clean of 32 (4-lane group), descending
#define CLEAN32(lane) { \
    u32 pr_[8]; \
    _Pragma("unroll") for (int i_ = 0; i_ < 8; ++i_) pr_[i_] = __shfl_xor(c[i_], 2); \
    { bool km_ = ((lane) & 2) == 0; \
      _Pragma("unroll") for (int i_ = 0; i_ < 8; ++i_) \
          c[i_] = km_ ? max(c[i_], pr_[i_]) : min(c[i_], pr_[i_]); } \
    _Pragma("unroll") for (int i_ = 0; i_ < 8; ++i_) pr_[i_] = __shfl_xor(c[i_], 1); \
    { bool km_ = ((lane) & 1) == 0; \
      _Pragma("unroll") for (int i_ = 0; i_ < 8; ++i_) \
          c[i_] = km_ ? max(c[i_], pr_[i_]) : min(c[i_], pr_[i_]); } \
    CLEAN8() }

// ---------- sel: merge-tree top-32 -> exact rescore -> sort-64 -> stats ----------
__global__ __launch_bounds__(256) void ec_sel(const u32* __restrict__ cand,
                                              const float* __restrict__ xt,
                                              const float* __restrict__ xx,
                                              const __half* __restrict__ u,
                                              const __half* __restrict__ v,
                                              const int* __restrict__ kptr,
                                              __half2* __restrict__ ext,
                                              float* __restrict__ statsR) {
    __shared__ float sxn[4][64];
    __shared__ int scand[4][32];
    __shared__ float rsum[256], rsum2[256];
    const int t = threadIdx.x, w = t >> 6, lane = t & 63;
    const int b = blockIdx.y;
    const int n = blockIdx.x * 4 + w;
    const int k = *kptr;

    const u32* cp = cand + (((size_t)b * N + n) * 64 + lane) * 8;
    uint4 a0 = *(const uint4*)cp, a1 = *(const uint4*)(cp + 4);
    u32 c[8] = { a0.x, a0.y, a0.z, a0.w, a1.x, a1.y, a1.z, a1.w };  // sorted desc

    // Step A (xor 1): lane-pairs -> sorted-16
    {
        u32 pr[8];
#pragma unroll
        for (int i = 0; i < 8; ++i) pr[i] = __shfl_xor(c[7 - i], 1);
        bool lo = (lane & 1) == 0;
#pragma unroll
        for (int i = 0; i < 8; ++i) {
            u32 mx = max(c[i], pr[i]), mn = min(c[i], pr[i]);
            c[i] = lo ? mx : mn;
        }
        CLEAN8()
    }
    // Step B (xor 2): pairs -> sorted-32 per 4-lane quad
    {
        u32 pr[8];
#pragma unroll
        for (int i = 0; i < 8; ++i) pr[i] = __shfl_xor(c[7 - i], 1);
        bool up = (lane & 2) != 0;
#pragma unroll
        for (int i = 0; i < 8; ++i) c[i] = up ? pr[i] : c[i];
        CLEAN32(lane)
    }
    // Steps C-F: butterfly top-32 halver with quads 4/8/16/32 apart
#define MERGE_TOP32(mask) { \
        u32 pr[8]; \
        _Pragma("unroll") for (int i = 0; i < 8; ++i) pr[i] = __shfl_xor(c[7 - i], mask); \
        _Pragma("unroll") for (int i = 0; i < 8; ++i) c[i] = max(c[i], pr[i]); \
        CLEAN32(lane) }
    MERGE_TOP32(7)
    MERGE_TOP32(11)
    MERGE_TOP32(19)
    MERGE_TOP32(35)
#undef MERGE_TOP32

    // lanes 0-3 hold global top-32 sorted desc: rank = lane*8 + reg
    if (lane < 4) {
        int base = lane * 8;
#pragma unroll
        for (int i = 0; i < 8; ++i) scand[w][base + i] = 4095 - (int)(c[i] & 0xFFFu);
    }
    sxn[w][lane] = xt[((size_t)b * N + n) * 64 + lane];
    __syncthreads();

    // exact fp32 rescore: lane = (candidate jc, c-half h)
    const float* xt_ = xt + (size_t)b * N * 64;
    const int jc = lane & 31, h = lane >> 5;
    const int mj = scand[w][jc];
    const float* xr = xt_ + (size_t)mj * 64 + h * 32;
    float acc = 0.f;
#pragma unroll
    for (int q8 = 0; q8 < 8; ++q8) {
        float4 g4 = *(const float4*)&xr[q8 * 4];
        float4 xn4 = *(const float4*)&sxn[w][h * 32 + q8 * 4];
        acc += g4.x * xn4.x + g4.y * xn4.y + g4.z * xn4.z + g4.w * xn4.w;
    }
    acc += __shfl_xor(acc, 32);
    float ex = 2.f * acc - xx[(size_t)b * N + mj];
    unsigned fu = __builtin_bit_cast(unsigned, ex);
    unsigned sf = fu ^ (unsigned)(((int)fu >> 31) | 0x80000000);
    u64 key = ((u64)sf << 12) | (u64)(4095 - mj);
    if (h) key = 0;                        // kill duplicate copy

    // descending bitonic sort of 64 u64 keys (1/lane)
#pragma unroll
    for (int ls = 1; ls <= 6; ++ls) {
        const int s = 1 << ls;
        const bool lb = (lane & s) == 0;
#pragma unroll
        for (int dd = s >> 1; dd >= 1; dd >>= 1) {
            const bool km = ((lane & dd) == 0) == lb;
            u64 pv = __shfl_xor(key, dd);
            u64 mn = key < pv ? key : pv;
            u64 mx = key < pv ? pv : key;
            key = km ? mx : mn;
        }
    }
    int m_final = 4095 - (int)(key & 0xFFFu);   // lane r = r-th best exact

    // fused BN stats gather: lane = o
    const __half* ub = u + (size_t)b * N * O;
    size_t rowb = (size_t)b * N + n;
    float vv = __half2float(v[rowb * O + lane]);
    float gmax = -FLT_MAX, gmin = FLT_MAX, gs = 0.f, gs2 = 0.f;
    if (k == 20) {
        int mks[20];
#pragma unroll
        for (int kk = 0; kk < 20; ++kk) mks[kk] = __shfl(m_final, kk);
        float g[20];
#pragma unroll
        for (int kk = 0; kk < 20; ++kk)
            g[kk] = __half2float(ub[(size_t)mks[kk] * O + lane]);
#pragma unroll
        for (int kk = 0; kk < 20; ++kk) {
            gs += g[kk]; gs2 += g[kk] * g[kk];
            gmax = fmaxf(gmax, g[kk]); gmin = fminf(gmin, g[kk]);
        }
    } else {
        int mks[KMAX];
#pragma unroll
        for (int kk = 0; kk < KMAX; ++kk) mks[kk] = __shfl(m_final, kk);
        float g[KMAX];
#pragma unroll
        for (int kk = 0; kk < KMAX; ++kk)
            g[kk] = __half2float(ub[(size_t)mks[kk] * O + lane]);
#pragma unroll
        for (int kk = 0; kk < KMAX; ++kk) {
            if (kk < k) {
                gs += g[kk]; gs2 += g[kk] * g[kk];
                gmax = fmaxf(gmax, g[kk]); gmin = fminf(gmin, g[kk]);
            }
        }
    }
    float fk = (float)k;
    float s  = gs + fk * vv;
    float s2 = gs2 + 2.f * vv * gs + fk * vv * vv;
    ext[rowb * O + lane] = __halves2half2(__float2half(gmax + vv), __float2half(gmin + vv));
    rsum[t] = s; rsum2[t] = s2;
    __syncthreads();
    if (t < 64) {
        float a  = rsum[t] + rsum[t + 64] + rsum[t + 128] + rsum[t + 192];
        float a2 = rsum2[t] + rsum2[t + 64] + rsum2[t + 128] + rsum2[t + 192];
        float* sr = statsR + (size_t)(blockIdx.x & (NREP - 1)) * 128;
        atomicAdd(&sr[t], a);
        atomicAdd(&sr[64 + t], a2);
    }
}

// ---------- finalize BN affine (reduce NREP replicas) ----------
__global__ void ec_final(const float* __restrict__ statsR,
                         const float* __restrict__ gamma,
                         const float* __restrict__ beta,
                         const int* __restrict__ kptr,
                         float* __restrict__ scsh) {
    int o = threadIdx.x;                   // 64
    int k = *kptr;
    float s = 0.f, s2 = 0.f;
    for (int r = 0; r < NREP; ++r) {
        s  += statsR[r * 128 + o];
        s2 += statsR[r * 128 + 64 + o];
    }
    float M = (float)B * (float)N * (float)k;
    float mean = s / M;
    float var = s2 / M - mean * mean;
    var = fmaxf(var, 0.f);
    float sc = gamma[o] * rsqrtf(var + 1e-5f);
    float sh = beta[o] - mean * sc;
    scsh[o] = sc;
    scsh[64 + o] = sh;
}

// ---------- output: pick extreme by sc sign, BN + leaky, transpose ----------
__global__ __launch_bounds__(256) void ec_out(const __half2* __restrict__ ext,
                                              const float* __restrict__ scsh,
                                              float* __restrict__ out) {
    __shared__ float res[64][65];
    const int blk = blockIdx.x;            // B*N/64
    const int b = blk >> 6;
    const int n0 = (blk & 63) << 6;
    const int t = threadIdx.x;
    {
        const int o = t & 63, ni = t >> 6;
        float sc = scsh[o], sh = scsh[64 + o];
#pragma unroll 1
        for (int p = 0; p < 16; ++p) {
            int nl = ni * 16 + p;
            size_t a = ((size_t)b * N + n0 + nl) * O + o;
            __half2 e = ext[a];
            float y = (sc >= 0.f) ? __low2float(e) : __high2float(e);
            float z = sc * y + sh;
            res[nl][o] = (z >= 0.f) ? z : 0.2f * z;
        }
    }
    __syncthreads();
    {
        const int j = t & 63, oi = t >> 6;
#pragma unroll 1
        for (int p = 0; p < 16; ++p) {
            int o2 = oi * 16 + p;
            out[(size_t)b * O * N + (size_t)o2 * N + n0 + j] = res[j][o2];
        }
    }
}

extern "C" void kernel_launch(void* const* d_in, const int* in_sizes, int n_in,
                              void* d_out, int out_size, void* d_ws, size_t ws_size,
                              hipStream_t stream) {
    const float* x     = (const float*)d_in[0];
    const float* W     = (const float*)d_in[1];
    const float* gamma = (const float*)d_in[2];
    const float* beta  = (const float*)d_in[3];
    const int*   kptr  = (const int*)d_in[4];
    float* out = (float*)d_out;

    char* ws = (char*)d_ws;
    u32*    cand = (u32*)ws;    ws += (size_t)B * N * 64 * 8 * 4;  // 64 MB
    float*  xx   = (float*)ws;  ws += (size_t)B * N * 4;
    float*  xt   = (float*)ws;  ws += (size_t)B * N * C * 4;       // 8 MB
    u16*    xtb  = (u16*)ws;    ws += (size_t)B * N * C * 2;       // 4 MB
    __half* u_t  = (__half*)ws; ws += (size_t)B * N * O * 2;       // 4 MB
    __half* v_t  = (__half*)ws; ws += (size_t)B * N * O * 2;       // 4 MB
    __half2* ext = (__half2*)ws; ws += (size_t)B * N * O * 4;      // 8 MB
    float* statsR = (float*)ws; ws += (size_t)NREP * 128 * 4;      // 32 KB
    float* scsh  = (float*)ws;

    hipMemsetAsync(statsR, 0, NREP * 128 * 4, stream);
    ec_prep<<<B * N / 64, 256, 0, stream>>>(x, W, xx, xt, xtb, u_t, v_t);
    ec_gemm<<<dim3(N / 128, N / 128, B), 256, 0, stream>>>(xtb, xx, cand);
    ec_sel<<<dim3(N / 4, B), 256, 0, stream>>>(cand, xt, xx, u_t, v_t, kptr, ext, statsR);
    ec_final<<<1, 64, 0, stream>>>(statsR, gamma, beta, kptr, scsh);
    ec_out<<<B * N / 64, 256, 0, stream>>>(ext, scsh, out);
}

// Round 10
// 207.470 us; speedup vs baseline: 2.4995x; 1.0796x over previous
//
#include <hip/hip_runtime.h>
#include <hip/hip_fp16.h>
#include <float.h>

#define B 8
#define C 64
#define N 4096
#define O 64
#define KMAX 32
#define NREP 64   // stats replica buffers (atomic contention divider)

typedef unsigned short u16;
typedef unsigned int u32;
typedef unsigned long long u64;
typedef __attribute__((ext_vector_type(8))) u16 u16x8;
typedef __attribute__((ext_vector_type(8))) short bf16x8;
typedef __attribute__((ext_vector_type(4))) float f32x4;

__device__ __forceinline__ u16 f2bf(float f) {
    unsigned u = __builtin_bit_cast(unsigned, f);
    unsigned r = (u + 0x7FFFu + ((u >> 16) & 1)) >> 16;   // RTNE
    return (u16)r;
}

// ---------- fused prep: xt fp32, xtb bf16, xx, u/v fp16 ----------
__global__ __launch_bounds__(256) void ec_prep(const float* __restrict__ x,
                                               const float* __restrict__ W,
                                               float* __restrict__ xx,
                                               float* __restrict__ xt,
                                               u16* __restrict__ xtb,
                                               __half* __restrict__ u,
                                               __half* __restrict__ v) {
    __shared__ float xs[64][65];
    __shared__ float W1[C][64];
    __shared__ float Wd[C][64];
    __shared__ float rs[4][64];
    const int blk = blockIdx.x;            // B*N/64 = 512
    const int b = blk >> 6;
    const int n0 = (blk & 63) << 6;
    const int t = threadIdx.x;
#pragma unroll
    for (int p = 0; p < 16; ++p) {
        int q = t + 256 * p; int c = q >> 6, j = q & 63;
        xs[c][j] = x[(size_t)b * C * N + (size_t)c * N + n0 + j];
    }
#pragma unroll
    for (int p = 0; p < 16; ++p) {
        int q = t + 256 * p; int c = q >> 6, o = q & 63;
        float w1 = W[o * 128 + c];
        float w2 = W[o * 128 + 64 + c];
        W1[c][o] = w1; Wd[c][o] = w2 - w1;
    }
    __syncthreads();
    {
        const int j = t >> 2, g = t & 3;
        float vals[16]; float ss = 0.f;
#pragma unroll
        for (int i = 0; i < 16; ++i) { float f = xs[g * 16 + i][j]; vals[i] = f; ss += f * f; }
        rs[g][j] = ss;
        size_t rowb = ((size_t)b * N + n0 + j) * 64 + g * 16;
#pragma unroll
        for (int i = 0; i < 4; ++i) {
            float4 v4 = { vals[4 * i], vals[4 * i + 1], vals[4 * i + 2], vals[4 * i + 3] };
            *(float4*)&xt[rowb + 4 * i] = v4;
        }
        u16x8 h0, h1;
#pragma unroll
        for (int i = 0; i < 8; ++i) { h0[i] = f2bf(vals[i]); h1[i] = f2bf(vals[8 + i]); }
        *(u16x8*)&xtb[rowb] = h0;
        *(u16x8*)&xtb[rowb + 8] = h1;
    }
    {
        const int o = t & 63, ji = t >> 6;
#pragma unroll 1
        for (int p = 0; p < 16; ++p) {
            int j = ji + 4 * p;
            float su = 0.f, sv = 0.f;
#pragma unroll
            for (int c = 0; c < C; ++c) {
                float xv = xs[c][j];
                su += xv * W1[c][o];
                sv += xv * Wd[c][o];
            }
            size_t base = ((size_t)b * N + n0 + j) * O + o;
            u[base] = __float2half(su);
            v[base] = __float2half(sv);
        }
    }
    __syncthreads();
    if (t < 64) xx[(size_t)b * N + t + n0] = rs[0][t] + rs[1][t] + rs[2][t] + rs[3][t];
}

// ---------- in-register compare-exchange (descending: first arg keeps max) ----------
#define CXD(a, b) { u32 mx_ = max(a, b); b = min(a, b); a = mx_; }
#define CXA(a, b) { u32 mn_ = min(a, b); b = max(a, b); a = mn_; }
// bitonic sort-8 descending on named regs (24 CX)
#define BSORT8(e0,e1,e2,e3,e4,e5,e6,e7) { \
    CXD(e0,e1) CXA(e2,e3) CXD(e4,e5) CXA(e6,e7) \
    CXD(e0,e2) CXD(e1,e3) CXA(e4,e6) CXA(e5,e7) \
    CXD(e0,e1) CXD(e2,e3) CXA(e4,e5) CXA(e6,e7) \
    CXD(e0,e4) CXD(e1,e5) CXD(e2,e6) CXD(e3,e7) \
    CXD(e0,e2) CXD(e1,e3) CXD(e4,e6) CXD(e5,e7) \
    CXD(e0,e1) CXD(e2,e3) CXD(e4,e5) CXD(e6,e7) }
// merge sorted-8 e into sorted-8 t keeping top-8 (8 max + 12 CX clean)
#define MERGETOP8(t0,t1,t2,t3,t4,t5,t6,t7, e0,e1,e2,e3,e4,e5,e6,e7) { \
    t0 = max(t0, e7); t1 = max(t1, e6); t2 = max(t2, e5); t3 = max(t3, e4); \
    t4 = max(t4, e3); t5 = max(t5, e2); t6 = max(t6, e1); t7 = max(t7, e0); \
    CXD(t0,t4) CXD(t1,t5) CXD(t2,t6) CXD(t3,t7) \
    CXD(t0,t2) CXD(t1,t3) CXD(t4,t6) CXD(t5,t7) \
    CXD(t0,t1) CXD(t2,t3) CXD(t4,t5) CXD(t6,t7) }

// ---------- MFMA distance + fused per-(row,64-col-chunk) top-8 ----------
// cand[((b*N+row)*64 + chunk)*8 + s] : packed u32 = (key16<<12)|(4095-m)
__global__ __launch_bounds__(256) void ec_gemm(const u16* __restrict__ xtb,
                                               const float* __restrict__ xx,
                                               u32* __restrict__ cand) {
    __shared__ u16 lds[18432 + 8];
    const int t = threadIdx.x;
    const int m0 = blockIdx.x * 128, n0 = blockIdx.y * 128;
    const int b = blockIdx.z;
    const u16* xa = xtb + (size_t)b * N * 64;
#pragma unroll
    for (int p = 0; p < 4; ++p) {
        int q = t + 256 * p;
        int row = q >> 3, ch = q & 7;
        int by = (row * 128 + ch * 16) ^ ((row & 7) << 4);
        *(u16x8*)((char*)lds + by) = *(const u16x8*)&xa[(size_t)(n0 + row) * 64 + ch * 8];
        *(u16x8*)((char*)lds + 16384 + by) = *(const u16x8*)&xa[(size_t)(m0 + row) * 64 + ch * 8];
    }
    __syncthreads();
    const int w = t >> 6, lane = t & 63;
    const int wr = w >> 1, wc = w & 1;
    const int fr = lane & 15, fg = lane >> 4;
    f32x4 acc[4][4] = {};
#pragma unroll
    for (int ks = 0; ks < 2; ++ks) {
        bf16x8 af[4], bg[4];
#pragma unroll
        for (int fi = 0; fi < 4; ++fi) {
            int rowA = 64 * wr + 16 * fi + fr;
            int byA = (rowA * 128 + ks * 64 + fg * 16) ^ ((rowA & 7) << 4);
            af[fi] = *(const bf16x8*)((const char*)lds + byA);
            int rowB = 64 * wc + 16 * fi + fr;
            int byB = (rowB * 128 + ks * 64 + fg * 16) ^ ((rowB & 7) << 4);
            bg[fi] = *(const bf16x8*)((const char*)lds + 16384 + byB);
        }
#pragma unroll
        for (int fi = 0; fi < 4; ++fi)
#pragma unroll
            for (int fj = 0; fj < 4; ++fj)
                acc[fi][fj] = __builtin_amdgcn_mfma_f32_16x16x32_bf16(af[fi], bg[fj], acc[fi][fj], 0, 0, 0);
    }
    float xm[4];
#pragma unroll
    for (int fj = 0; fj < 4; ++fj) xm[fj] = xx[(size_t)b * N + m0 + 64 * wc + 16 * fj + fr];
    __syncthreads();                        // staging LDS dead; reuse for epilogue
    u16* ep = lds + w * 4608;               // 64 rows x stride 72 u16 (144 B, 16B-aligned)
#pragma unroll
    for (int fi = 0; fi < 4; ++fi)
#pragma unroll
        for (int fj = 0; fj < 4; ++fj)
#pragma unroll
            for (int r = 0; r < 4; ++r) {
                float dv = 2.f * acc[fi][fj][r] - xm[fj];
                unsigned fu = __builtin_bit_cast(unsigned, dv);
                unsigned sf = fu ^ (unsigned)(((int)fu >> 31) | 0x80000000);
                int row = 16 * fi + fg * 4 + r, col = 16 * fj + fr;
                ep[row * 72 + col] = (u16)((sf + 0x8000u) >> 16);   // rounded sortable key
            }
    __syncthreads();
    // per-lane: row = lane; sorting-network top-8 over 64 cols
    const u16* myrow = lds + w * 4608 + lane * 72;
    const int mbase = m0 + (wc << 6);
    const u32 invb = (u32)(4095 - mbase);   // wave-uniform
    u32 t0, t1, t2, t3, t4, t5, t6, t7;
    {
        u16x8 q = *(const u16x8*)&myrow[0];
        t0 = ((u32)q[0] << 12) + invb - 0; t1 = ((u32)q[1] << 12) + invb - 1;
        t2 = ((u32)q[2] << 12) + invb - 2; t3 = ((u32)q[3] << 12) + invb - 3;
        t4 = ((u32)q[4] << 12) + invb - 4; t5 = ((u32)q[5] << 12) + invb - 5;
        t6 = ((u32)q[6] << 12) + invb - 6; t7 = ((u32)q[7] << 12) + invb - 7;
        BSORT8(t0, t1, t2, t3, t4, t5, t6, t7)
    }
#pragma unroll
    for (int g = 1; g < 8; ++g) {
        u16x8 q = *(const u16x8*)&myrow[g * 8];
        u32 base = invb - (u32)(g * 8);
        u32 e0 = ((u32)q[0] << 12) + base - 0, e1 = ((u32)q[1] << 12) + base - 1;
        u32 e2 = ((u32)q[2] << 12) + base - 2, e3 = ((u32)q[3] << 12) + base - 3;
        u32 e4 = ((u32)q[4] << 12) + base - 4, e5 = ((u32)q[5] << 12) + base - 5;
        u32 e6 = ((u32)q[6] << 12) + base - 6, e7 = ((u32)q[7] << 12) + base - 7;
        BSORT8(e0, e1, e2, e3, e4, e5, e6, e7)
        MERGETOP8(t0, t1, t2, t3, t4, t5, t6, t7, e0, e1, e2, e3, e4, e5, e6, e7)
    }
    const int row_g = n0 + 64 * wr + lane;
    u32* cp = cand + (((size_t)b * N + row_g) * 64 + (size_t)(blockIdx.x * 2 + wc)) * 8;
    uint4 w0 = { t0, t1, t2, t3 }, w1 = { t4, t5, t6, t7 };
    *(uint4*)cp = w0;
    *(uint4*)(cp + 4) = w1;
}

// ---------- merge-tree helpers (in-register, 8 keys/lane) ----------
#define CXI(i, j) { u32 mn_ = min(c[i], c[j]); c[i] = max(c[i], c[j]); c[j] = mn_; }
#define CLEAN8() { CXI(0,4) CXI(1,5) CXI(2,6) CXI(3,7) \
                   CXI(0,2) CXI(1,3) CXI(4,6) CXI(5,7) \
                   CXI(0,1) CXI(2,3) CXI(4,5) CXI(6,7) }
// distributed bitonic clean of 32 (4-lane group), descending
#define CLEAN32(lane) { \
    u32 pr_[8]; \
    _Pragma("unroll") for (int i_ = 0; i_ < 8; ++i_) pr_[i_] = __shfl_xor(c[i_], 2); \
    { bool km_ = ((lane) & 2) == 0; \
      _Pragma("unroll") for (int i_ = 0; i_ < 8; ++i_) \
          c[i_] = km_ ? max(c[i_], pr_[i_]) : min(c[i_], pr_[i_]); } \
    _Pragma("unroll") for (int i_ = 0; i_ < 8; ++i_) pr_[i_] = __shfl_xor(c[i_], 1); \
    { bool km_ = ((lane) & 1) == 0; \
      _Pragma("unroll") for (int i_ = 0; i_ < 8; ++i_) \
          c[i_] = km_ ? max(c[i_], pr_[i_]) : min(c[i_], pr_[i_]); } \
    CLEAN8() }

// ---------- sel: merge-tree top-32 -> exact rescore -> sort-64 -> stats ----------
__global__ __launch_bounds__(256) void ec_sel(const u32* __restrict__ cand,
                                              const float* __restrict__ xt,
                                              const float* __restrict__ xx,
                                              const __half* __restrict__ u,
                                              const __half* __restrict__ v,
                                              const int* __restrict__ kptr,
                                              __half2* __restrict__ ext,
                                              float* __restrict__ statsR) {
    __shared__ float sxn[4][64];
    __shared__ int scand[4][32];
    __shared__ float rsum[256], rsum2[256];
    const int t = threadIdx.x, w = t >> 6, lane = t & 63;
    const int b = blockIdx.y;
    const int n = blockIdx.x * 4 + w;
    const int k = *kptr;

    const u32* cp = cand + (((size_t)b * N + n) * 64 + lane) * 8;
    uint4 a0 = *(const uint4*)cp, a1 = *(const uint4*)(cp + 4);
    u32 c[8] = { a0.x, a0.y, a0.z, a0.w, a1.x, a1.y, a1.z, a1.w };  // sorted desc

    // Step A (xor 1): lane-pairs -> sorted-16
    {
        u32 pr[8];
#pragma unroll
        for (int i = 0; i < 8; ++i) pr[i] = __shfl_xor(c[7 - i], 1);
        bool lo = (lane & 1) == 0;
#pragma unroll
        for (int i = 0; i < 8; ++i) {
            u32 mx = max(c[i], pr[i]), mn = min(c[i], pr[i]);
            c[i] = lo ? mx : mn;
        }
        CLEAN8()
    }
    // Step B (xor 2): pairs -> sorted-32 per 4-lane quad
    {
        u32 pr[8];
#pragma unroll
        for (int i = 0; i < 8; ++i) pr[i] = __shfl_xor(c[7 - i], 1);
        bool up = (lane & 2) != 0;
#pragma unroll
        for (int i = 0; i < 8; ++i) c[i] = up ? pr[i] : c[i];
        CLEAN32(lane)
    }
    // Steps C-F: butterfly top-32 halver with quads 4/8/16/32 apart
#define MERGE_TOP32(mask) { \
        u32 pr[8]; \
        _Pragma("unroll") for (int i = 0; i < 8; ++i) pr[i] = __shfl_xor(c[7 - i], mask); \
        _Pragma("unroll") for (int i = 0; i < 8; ++i) c[i] = max(c[i], pr[i]); \
        CLEAN32(lane) }
    MERGE_TOP32(7)
    MERGE_TOP32(11)
    MERGE_TOP32(19)
    MERGE_TOP32(35)
#undef MERGE_TOP32

    // lanes 0-3 hold global top-32 sorted desc: rank = lane*8 + reg
    if (lane < 4) {
        int base = lane * 8;
#pragma unroll
        for (int i = 0; i < 8; ++i) scand[w][base + i] = 4095 - (int)(c[i] & 0xFFFu);
    }
    sxn[w][lane] = xt[((size_t)b * N + n) * 64 + lane];
    __syncthreads();

    // exact fp32 rescore: lane = (candidate jc, c-half h)
    const float* xt_ = xt + (size_t)b * N * 64;
    const int jc = lane & 31, h = lane >> 5;
    const int mj = scand[w][jc];
    const float* xr = xt_ + (size_t)mj * 64 + h * 32;
    float acc = 0.f;
#pragma unroll
    for (int q8 = 0; q8 < 8; ++q8) {
        float4 g4 = *(const float4*)&xr[q8 * 4];
        float4 xn4 = *(const float4*)&sxn[w][h * 32 + q8 * 4];
        acc += g4.x * xn4.x + g4.y * xn4.y + g4.z * xn4.z + g4.w * xn4.w;
    }
    acc += __shfl_xor(acc, 32);
    float ex = 2.f * acc - xx[(size_t)b * N + mj];
    unsigned fu = __builtin_bit_cast(unsigned, ex);
    unsigned sf = fu ^ (unsigned)(((int)fu >> 31) | 0x80000000);
    u64 key = ((u64)sf << 12) | (u64)(4095 - mj);
    if (h) key = 0;                        // kill duplicate copy

    // descending bitonic sort of 64 u64 keys (1/lane)
#pragma unroll
    for (int ls = 1; ls <= 6; ++ls) {
        const int s = 1 << ls;
        const bool lb = (lane & s) == 0;
#pragma unroll
        for (int dd = s >> 1; dd >= 1; dd >>= 1) {
            const bool km = ((lane & dd) == 0) == lb;
            u64 pv = __shfl_xor(key, dd);
            u64 mn = key < pv ? key : pv;
            u64 mx = key < pv ? pv : key;
            key = km ? mx : mn;
        }
    }
    int m_final = 4095 - (int)(key & 0xFFFu);   // lane r = r-th best exact

    // fused BN stats gather: lane = o
    const __half* ub = u + (size_t)b * N * O;
    size_t rowb = (size_t)b * N + n;
    float vv = __half2float(v[rowb * O + lane]);
    float gmax = -FLT_MAX, gmin = FLT_MAX, gs = 0.f, gs2 = 0.f;
    if (k == 20) {
        int mks[20];
#pragma unroll
        for (int kk = 0; kk < 20; ++kk) mks[kk] = __shfl(m_final, kk);
        float g[20];
#pragma unroll
        for (int kk = 0; kk < 20; ++kk)
            g[kk] = __half2float(ub[(size_t)mks[kk] * O + lane]);
#pragma unroll
        for (int kk = 0; kk < 20; ++kk) {
            gs += g[kk]; gs2 += g[kk] * g[kk];
            gmax = fmaxf(gmax, g[kk]); gmin = fminf(gmin, g[kk]);
        }
    } else {
        int mks[KMAX];
#pragma unroll
        for (int kk = 0; kk < KMAX; ++kk) mks[kk] = __shfl(m_final, kk);
        float g[KMAX];
#pragma unroll
        for (int kk = 0; kk < KMAX; ++kk)
            g[kk] = __half2float(ub[(size_t)mks[kk] * O + lane]);
#pragma unroll
        for (int kk = 0; kk < KMAX; ++kk) {
            if (kk < k) {
                gs += g[kk]; gs2 += g[kk] * g[kk];
                gmax = fmaxf(gmax, g[kk]); gmin = fminf(gmin, g[kk]);
            }
        }
    }
    float fk = (float)k;
    float s  = gs + fk * vv;
    float s2 = gs2 + 2.f * vv * gs + fk * vv * vv;
    ext[rowb * O + lane] = __halves2half2(__float2half(gmax + vv), __float2half(gmin + vv));
    rsum[t] = s; rsum2[t] = s2;
    __syncthreads();
    if (t < 64) {
        float a  = rsum[t] + rsum[t + 64] + rsum[t + 128] + rsum[t + 192];
        float a2 = rsum2[t] + rsum2[t + 64] + rsum2[t + 128] + rsum2[t + 192];
        float* sr = statsR + (size_t)(blockIdx.x & (NREP - 1)) * 128;
        atomicAdd(&sr[t], a);
        atomicAdd(&sr[64 + t], a2);
    }
}

// ---------- finalize BN affine (reduce NREP replicas) ----------
__global__ void ec_final(const float* __restrict__ statsR,
                         const float* __restrict__ gamma,
                         const float* __restrict__ beta,
                         const int* __restrict__ kptr,
                         float* __restrict__ scsh) {
    int o = threadIdx.x;                   // 64
    int k = *kptr;
    float s = 0.f, s2 = 0.f;
    for (int r = 0; r < NREP; ++r) {
        s  += statsR[r * 128 + o];
        s2 += statsR[r * 128 + 64 + o];
    }
    float M = (float)B * (float)N * (float)k;
    float mean = s / M;
    float var = s2 / M - mean * mean;
    var = fmaxf(var, 0.f);
    float sc = gamma[o] * rsqrtf(var + 1e-5f);
    float sh = beta[o] - mean * sc;
    scsh[o] = sc;
    scsh[64 + o] = sh;
}

// ---------- output: pick extreme by sc sign, BN + leaky, transpose ----------
__global__ __launch_bounds__(256) void ec_out(const __half2* __restrict__ ext,
                                              const float* __restrict__ scsh,
                                              float* __restrict__ out) {
    __shared__ float res[64][65];
    const int blk = blockIdx.x;            // B*N/64
    const int b = blk >> 6;
    const int n0 = (blk & 63) << 6;
    const int t = threadIdx.x;
    {
        const int o = t & 63, ni = t >> 6;
        float sc = scsh[o], sh = scsh[64 + o];
#pragma unroll 1
        for (int p = 0; p < 16; ++p) {
            int nl = ni * 16 + p;
            size_t a = ((size_t)b * N + n0 + nl) * O + o;
            __half2 e = ext[a];
            float y = (sc >= 0.f) ? __low2float(e) : __high2float(e);
            float z = sc * y + sh;
            res[nl][o] = (z >= 0.f) ? z : 0.2f * z;
        }
    }
    __syncthreads();
    {
        const int j = t & 63, oi = t >> 6;
#pragma unroll 1
        for (int p = 0; p < 16; ++p) {
            int o2 = oi * 16 + p;
            out[(size_t)b * O * N + (size_t)o2 * N + n0 + j] = res[j][o2];
        }
    }
}

extern "C" void kernel_launch(void* const* d_in, const int* in_sizes, int n_in,
                              void* d_out, int out_size, void* d_ws, size_t ws_size,
                              hipStream_t stream) {
    const float* x     = (const float*)d_in[0];
    const float* W     = (const float*)d_in[1];
    const float* gamma = (const float*)d_in[2];
    const float* beta  = (const float*)d_in[3];
    const int*   kptr  = (const int*)d_in[4];
    float* out = (float*)d_out;

    char* ws = (char*)d_ws;
    u32*    cand = (u32*)ws;    ws += (size_t)B * N * 64 * 8 * 4;  // 64 MB
    float*  xx   = (float*)ws;  ws += (size_t)B * N * 4;
    float*  xt   = (float*)ws;  ws += (size_t)B * N * C * 4;       // 8 MB
    u16*    xtb  = (u16*)ws;    ws += (size_t)B * N * C * 2;       // 4 MB
    __half* u_t  = (__half*)ws; ws += (size_t)B * N * O * 2;       // 4 MB
    __half* v_t  = (__half*)ws; ws += (size_t)B * N * O * 2;       // 4 MB
    __half2* ext = (__half2*)ws; ws += (size_t)B * N * O * 4;      // 8 MB
    float* statsR = (float*)ws; ws += (size_t)NREP * 128 * 4;      // 32 KB
    float* scsh  = (float*)ws;

    hipMemsetAsync(statsR, 0, NREP * 128 * 4, stream);
    ec_prep<<<B * N / 64, 256, 0, stream>>>(x, W, xx, xt, xtb, u_t, v_t);
    ec_gemm<<<dim3(N / 128, N / 128, B), 256, 0, stream>>>(xtb, xx, cand);
    ec_sel<<<dim3(N / 4, B), 256, 0, stream>>>(cand, xt, xx, u_t, v_t, kptr, ext, statsR);
    ec_final<<<1, 64, 0, stream>>>(statsR, gamma, beta, kptr, scsh);
    ec_out<<<B * N / 64, 256, 0, stream>>>(ext, scsh, out);
}

// Round 11
// 172.050 us; speedup vs baseline: 3.0141x; 1.2059x over previous
//
#include <hip/hip_runtime.h>
#include <hip/hip_fp16.h>
#include <float.h>

#define B 8
#define C 64
#define N 4096
#define O 64
#define KMAX 32
#define NREP 64   // stats replica buffers (atomic contention divider)

typedef unsigned short u16;
typedef unsigned int u32;
typedef unsigned long long u64;
typedef __attribute__((ext_vector_type(8))) u16 u16x8;
typedef __attribute__((ext_vector_type(8))) short bf16x8;
typedef __attribute__((ext_vector_type(4))) float f32x4;

__device__ __forceinline__ u16 f2bf(float f) {
    unsigned u = __builtin_bit_cast(unsigned, f);
    unsigned r = (u + 0x7FFFu + ((u >> 16) & 1)) >> 16;   // RTNE
    return (u16)r;
}

// ---------- fused prep: xt fp32, xtb bf16, xx, u/v fp16 ----------
__global__ __launch_bounds__(256) void ec_prep(const float* __restrict__ x,
                                               const float* __restrict__ W,
                                               float* __restrict__ xx,
                                               float* __restrict__ xt,
                                               u16* __restrict__ xtb,
                                               __half* __restrict__ u,
                                               __half* __restrict__ v) {
    __shared__ float xs[64][65];
    __shared__ float W1[C][64];
    __shared__ float Wd[C][64];
    __shared__ float rs[4][64];
    const int blk = blockIdx.x;            // B*N/64 = 512
    const int b = blk >> 6;
    const int n0 = (blk & 63) << 6;
    const int t = threadIdx.x;
#pragma unroll
    for (int p = 0; p < 16; ++p) {
        int q = t + 256 * p; int c = q >> 6, j = q & 63;
        xs[c][j] = x[(size_t)b * C * N + (size_t)c * N + n0 + j];
    }
#pragma unroll
    for (int p = 0; p < 16; ++p) {
        int q = t + 256 * p; int c = q >> 6, o = q & 63;
        float w1 = W[o * 128 + c];
        float w2 = W[o * 128 + 64 + c];
        W1[c][o] = w1; Wd[c][o] = w2 - w1;
    }
    __syncthreads();
    {
        const int j = t >> 2, g = t & 3;
        float vals[16]; float ss = 0.f;
#pragma unroll
        for (int i = 0; i < 16; ++i) { float f = xs[g * 16 + i][j]; vals[i] = f; ss += f * f; }
        rs[g][j] = ss;
        size_t rowb = ((size_t)b * N + n0 + j) * 64 + g * 16;
#pragma unroll
        for (int i = 0; i < 4; ++i) {
            float4 v4 = { vals[4 * i], vals[4 * i + 1], vals[4 * i + 2], vals[4 * i + 3] };
            *(float4*)&xt[rowb + 4 * i] = v4;
        }
        u16x8 h0, h1;
#pragma unroll
        for (int i = 0; i < 8; ++i) { h0[i] = f2bf(vals[i]); h1[i] = f2bf(vals[8 + i]); }
        *(u16x8*)&xtb[rowb] = h0;
        *(u16x8*)&xtb[rowb + 8] = h1;
    }
    // phase B: u/v projection, c-outer (W1/Wd read once per c, xs broadcast)
    {
        const int o = t & 63, ji = t >> 6;
        float su[16] = {}, sv[16] = {};
#pragma unroll 1
        for (int c = 0; c < C; ++c) {
            float w1 = W1[c][o];
            float wd = Wd[c][o];
#pragma unroll
            for (int p = 0; p < 16; ++p) {
                float xv = xs[c][ji + 4 * p];
                su[p] = fmaf(xv, w1, su[p]);
                sv[p] = fmaf(xv, wd, sv[p]);
            }
        }
#pragma unroll
        for (int p = 0; p < 16; ++p) {
            size_t base = ((size_t)b * N + n0 + ji + 4 * p) * O + o;
            u[base] = __float2half(su[p]);
            v[base] = __float2half(sv[p]);
        }
    }
    __syncthreads();
    if (t < 64) xx[(size_t)b * N + t + n0] = rs[0][t] + rs[1][t] + rs[2][t] + rs[3][t];
}

// ---------- in-register compare-exchange (descending: first arg keeps max) ----------
#define CXD(a, b) { u32 mx_ = max(a, b); b = min(a, b); a = mx_; }
#define CXA(a, b) { u32 mn_ = min(a, b); b = max(a, b); a = mn_; }
// bitonic sort-8 descending on named regs (24 CX)
#define BSORT8(e0,e1,e2,e3,e4,e5,e6,e7) { \
    CXD(e0,e1) CXA(e2,e3) CXD(e4,e5) CXA(e6,e7) \
    CXD(e0,e2) CXD(e1,e3) CXA(e4,e6) CXA(e5,e7) \
    CXD(e0,e1) CXD(e2,e3) CXA(e4,e5) CXA(e6,e7) \
    CXD(e0,e4) CXD(e1,e5) CXD(e2,e6) CXD(e3,e7) \
    CXD(e0,e2) CXD(e1,e3) CXD(e4,e6) CXD(e5,e7) \
    CXD(e0,e1) CXD(e2,e3) CXD(e4,e5) CXD(e6,e7) }
// merge sorted-8 e into sorted-8 t keeping top-8 (8 max + 12 CX clean)
#define MERGETOP8(t0,t1,t2,t3,t4,t5,t6,t7, e0,e1,e2,e3,e4,e5,e6,e7) { \
    t0 = max(t0, e7); t1 = max(t1, e6); t2 = max(t2, e5); t3 = max(t3, e4); \
    t4 = max(t4, e3); t5 = max(t5, e2); t6 = max(t6, e1); t7 = max(t7, e0); \
    CXD(t0,t4) CXD(t1,t5) CXD(t2,t6) CXD(t3,t7) \
    CXD(t0,t2) CXD(t1,t3) CXD(t4,t6) CXD(t5,t7) \
    CXD(t0,t1) CXD(t2,t3) CXD(t4,t5) CXD(t6,t7) }

// ---------- MFMA distance + fused per-(row,64-col-chunk) top-8 ----------
// Key: dvp = 2*acc - xm + 1536 in (736,1736) -> all fp32 bits share top byte
// 0x44 -> (u16)(bits>>8) is monotone in d. cand packed u32 = (key16<<12)|(4095-m)
__global__ __launch_bounds__(256) void ec_gemm(const u16* __restrict__ xtb,
                                               const float* __restrict__ xx,
                                               u32* __restrict__ cand) {
    __shared__ u16 lds[18432 + 8];
    const int t = threadIdx.x;
    const int m0 = blockIdx.x * 128, n0 = blockIdx.y * 128;
    const int b = blockIdx.z;
    const u16* xa = xtb + (size_t)b * N * 64;
#pragma unroll
    for (int p = 0; p < 4; ++p) {
        int q = t + 256 * p;
        int row = q >> 3, ch = q & 7;
        int by = (row * 128 + ch * 16) ^ ((row & 7) << 4);
        *(u16x8*)((char*)lds + by) = *(const u16x8*)&xa[(size_t)(n0 + row) * 64 + ch * 8];
        *(u16x8*)((char*)lds + 16384 + by) = *(const u16x8*)&xa[(size_t)(m0 + row) * 64 + ch * 8];
    }
    __syncthreads();
    const int w = t >> 6, lane = t & 63;
    const int wr = w >> 1, wc = w & 1;
    const int fr = lane & 15, fg = lane >> 4;
    f32x4 acc[4][4] = {};
#pragma unroll
    for (int ks = 0; ks < 2; ++ks) {
        bf16x8 af[4], bg[4];
#pragma unroll
        for (int fi = 0; fi < 4; ++fi) {
            int rowA = 64 * wr + 16 * fi + fr;
            int byA = (rowA * 128 + ks * 64 + fg * 16) ^ ((rowA & 7) << 4);
            af[fi] = *(const bf16x8*)((const char*)lds + byA);
            int rowB = 64 * wc + 16 * fi + fr;
            int byB = (rowB * 128 + ks * 64 + fg * 16) ^ ((rowB & 7) << 4);
            bg[fi] = *(const bf16x8*)((const char*)lds + 16384 + byB);
        }
#pragma unroll
        for (int fi = 0; fi < 4; ++fi)
#pragma unroll
            for (int fj = 0; fj < 4; ++fj)
                acc[fi][fj] = __builtin_amdgcn_mfma_f32_16x16x32_bf16(af[fi], bg[fj], acc[fi][fj], 0, 0, 0);
    }
    float xmK[4];
#pragma unroll
    for (int fj = 0; fj < 4; ++fj)
        xmK[fj] = 1536.f - xx[(size_t)b * N + m0 + 64 * wc + 16 * fj + fr];
    __syncthreads();                        // staging LDS dead; reuse for epilogue
    u16* ep = lds + w * 4608;               // 64 rows x stride 72 u16 (144 B, 16B-aligned)
#pragma unroll
    for (int fi = 0; fi < 4; ++fi)
#pragma unroll
        for (int fj = 0; fj < 4; ++fj)
#pragma unroll
            for (int r = 0; r < 4; ++r) {
                float dvp = fmaf(2.f, acc[fi][fj][r], xmK[fj]);   // dv + 1536 > 0
                u32 bits = __builtin_bit_cast(u32, dvp);
                int row = 16 * fi + fg * 4 + r, col = 16 * fj + fr;
                ep[row * 72 + col] = (u16)(bits >> 8);            // monotone key
            }
    __syncthreads();
    // per-lane: row = lane; sorting-network top-8 over 64 cols
    const u16* myrow = lds + w * 4608 + lane * 72;
    const int mbase = m0 + (wc << 6);
    const u32 invb = (u32)(4095 - mbase);   // wave-uniform
    u32 t0, t1, t2, t3, t4, t5, t6, t7;
    {
        u16x8 q = *(const u16x8*)&myrow[0];
        t0 = ((u32)q[0] << 12) | (invb - 0); t1 = ((u32)q[1] << 12) | (invb - 1);
        t2 = ((u32)q[2] << 12) | (invb - 2); t3 = ((u32)q[3] << 12) | (invb - 3);
        t4 = ((u32)q[4] << 12) | (invb - 4); t5 = ((u32)q[5] << 12) | (invb - 5);
        t6 = ((u32)q[6] << 12) | (invb - 6); t7 = ((u32)q[7] << 12) | (invb - 7);
        BSORT8(t0, t1, t2, t3, t4, t5, t6, t7)
    }
#pragma unroll
    for (int g = 1; g < 8; ++g) {
        u16x8 q = *(const u16x8*)&myrow[g * 8];
        const u32 inv0 = invb - (u32)(g * 8);  // wave-uniform
        u32 e0 = ((u32)q[0] << 12) | (inv0 - 0), e1 = ((u32)q[1] << 12) | (inv0 - 1);
        u32 e2 = ((u32)q[2] << 12) | (inv0 - 2), e3 = ((u32)q[3] << 12) | (inv0 - 3);
        u32 e4 = ((u32)q[4] << 12) | (inv0 - 4), e5 = ((u32)q[5] << 12) | (inv0 - 5);
        u32 e6 = ((u32)q[6] << 12) | (inv0 - 6), e7 = ((u32)q[7] << 12) | (inv0 - 7);
        BSORT8(e0, e1, e2, e3, e4, e5, e6, e7)
        MERGETOP8(t0, t1, t2, t3, t4, t5, t6, t7, e0, e1, e2, e3, e4, e5, e6, e7)
    }
    const int row_g = n0 + 64 * wr + lane;
    u32* cp = cand + (((size_t)b * N + row_g) * 64 + (size_t)(blockIdx.x * 2 + wc)) * 8;
    uint4 w0 = { t0, t1, t2, t3 }, w1 = { t4, t5, t6, t7 };
    *(uint4*)cp = w0;
    *(uint4*)(cp + 4) = w1;
}

// ---------- merge-tree helpers (in-register, 8 keys/lane) ----------
#define CXI(i, j) { u32 mn_ = min(c[i], c[j]); c[i] = max(c[i], c[j]); c[j] = mn_; }
#define CLEAN8() { CXI(0,4) CXI(1,5) CXI(2,6) CXI(3,7) \
                   CXI(0,2) CXI(1,3) CXI(4,6) CXI(5,7) \
                   CXI(0,1) CXI(2,3) CXI(4,5) CXI(6,7) }
// distributed bitonic clean of 32 (4-lane group), descending
#define CLEAN32(lane) { \
    u32 pr_[8]; \
    _Pragma("unroll") for (int i_ = 0; i_ < 8; ++i_) pr_[i_] = __shfl_xor(c[i_], 2); \
    { bool km_ = ((lane) & 2) == 0; \
      _Pragma("unroll") for (int i_ = 0; i_ < 8; ++i_) \
          c[i_] = km_ ? max(c[i_], pr_[i_]) : min(c[i_], pr_[i_]); } \
    _Pragma("unroll") for (int i_ = 0; i_ < 8; ++i_) pr_[i_] = __shfl_xor(c[i_], 1); \
    { bool km_ = ((lane) & 1) == 0; \
      _Pragma("unroll") for (int i_ = 0; i_ < 8; ++i_) \
          c[i_] = km_ ? max(c[i_], pr_[i_]) : min(c[i_], pr_[i_]); } \
    CLEAN8() }

// ---------- sel: merge-tree top-32 -> exact rescore -> sort-32 -> stats ----------
__global__ __launch_bounds__(256) void ec_sel(const u32* __restrict__ cand,
                                              const float* __restrict__ xt,
                                              const float* __restrict__ xx,
                                              const __half* __restrict__ u,
                                              const __half* __restrict__ v,
                                              const int* __restrict__ kptr,
                                              __half2* __restrict__ ext,
                                              float* __restrict__ statsR) {
    __shared__ float sxn[4][64];
    __shared__ int scand[4][32];
    __shared__ float rsum[256], rsum2[256];
    const int t = threadIdx.x, w = t >> 6, lane = t & 63;
    const int b = blockIdx.y;
    const int n = blockIdx.x * 4 + w;
    const int k = *kptr;

    const u32* cp = cand + (((size_t)b * N + n) * 64 + lane) * 8;
    uint4 a0 = *(const uint4*)cp, a1 = *(const uint4*)(cp + 4);
    u32 c[8] = { a0.x, a0.y, a0.z, a0.w, a1.x, a1.y, a1.z, a1.w };  // sorted desc

    // Step A (xor 1): lane-pairs -> sorted-16
    {
        u32 pr[8];
#pragma unroll
        for (int i = 0; i < 8; ++i) pr[i] = __shfl_xor(c[7 - i], 1);
        bool lo = (lane & 1) == 0;
#pragma unroll
        for (int i = 0; i < 8; ++i) {
            u32 mx = max(c[i], pr[i]), mn = min(c[i], pr[i]);
            c[i] = lo ? mx : mn;
        }
        CLEAN8()
    }
    // Step B (xor 2): pairs -> sorted-32 per 4-lane quad
    {
        u32 pr[8];
#pragma unroll
        for (int i = 0; i < 8; ++i) pr[i] = __shfl_xor(c[7 - i], 1);
        bool up = (lane & 2) != 0;
#pragma unroll
        for (int i = 0; i < 8; ++i) c[i] = up ? pr[i] : c[i];
        CLEAN32(lane)
    }
    // Steps C-F: butterfly top-32 halver with quads 4/8/16/32 apart
#define MERGE_TOP32(mask) { \
        u32 pr[8]; \
        _Pragma("unroll") for (int i = 0; i < 8; ++i) pr[i] = __shfl_xor(c[7 - i], mask); \
        _Pragma("unroll") for (int i = 0; i < 8; ++i) c[i] = max(c[i], pr[i]); \
        CLEAN32(lane) }
    MERGE_TOP32(7)
    MERGE_TOP32(11)
    MERGE_TOP32(19)
    MERGE_TOP32(35)
#undef MERGE_TOP32

    // lanes 0-3 hold global top-32 sorted desc: rank = lane*8 + reg
    if (lane < 4) {
        int base = lane * 8;
#pragma unroll
        for (int i = 0; i < 8; ++i) scand[w][base + i] = 4095 - (int)(c[i] & 0xFFFu);
    }
    sxn[w][lane] = xt[((size_t)b * N + n) * 64 + lane];
    __syncthreads();

    // exact fp32 rescore: lane = (candidate jc, c-half h)
    const float* xt_ = xt + (size_t)b * N * 64;
    const int jc = lane & 31, h = lane >> 5;
    const int mj = scand[w][jc];
    const float* xr = xt_ + (size_t)mj * 64 + h * 32;
    float acc = 0.f;
#pragma unroll
    for (int q8 = 0; q8 < 8; ++q8) {
        float4 g4 = *(const float4*)&xr[q8 * 4];
        float4 xn4 = *(const float4*)&sxn[w][h * 32 + q8 * 4];
        acc += g4.x * xn4.x + g4.y * xn4.y + g4.z * xn4.z + g4.w * xn4.w;
    }
    acc += __shfl_xor(acc, 32);
    float ex = 2.f * acc - xx[(size_t)b * N + mj];
    unsigned fu = __builtin_bit_cast(unsigned, ex);
    unsigned sf = fu ^ (unsigned)(((int)fu >> 31) | 0x80000000);
    u64 key = ((u64)sf << 12) | (u64)(4095 - mj);
    if (h) key = 0;                        // duplicate copy lives in lanes 32..63

    // descending bitonic sort of 32 u64 keys (lanes 0..31; halves isolated)
#pragma unroll
    for (int ls = 1; ls <= 5; ++ls) {
        const int s = 1 << ls;
        const bool lb = (lane & s) == 0;
#pragma unroll
        for (int dd = s >> 1; dd >= 1; dd >>= 1) {
            const bool km = ((lane & dd) == 0) == lb;
            u64 pv = __shfl_xor(key, dd);
            u64 mn = key < pv ? key : pv;
            u64 mx = key < pv ? pv : key;
            key = km ? mx : mn;
        }
    }
    int m_final = 4095 - (int)(key & 0xFFFu);   // lane r (<32) = r-th best exact

    // fused BN stats gather: lane = o
    const __half* ub = u + (size_t)b * N * O;
    size_t rowb = (size_t)b * N + n;
    float vv = __half2float(v[rowb * O + lane]);
    float gmax = -FLT_MAX, gmin = FLT_MAX, gs = 0.f, gs2 = 0.f;
    if (k == 20) {
        int mks[20];
#pragma unroll
        for (int kk = 0; kk < 20; ++kk) mks[kk] = __shfl(m_final, kk);
        float g[20];
#pragma unroll
        for (int kk = 0; kk < 20; ++kk)
            g[kk] = __half2float(ub[(size_t)mks[kk] * O + lane]);
#pragma unroll
        for (int kk = 0; kk < 20; ++kk) {
            gs += g[kk]; gs2 += g[kk] * g[kk];
            gmax = fmaxf(gmax, g[kk]); gmin = fminf(gmin, g[kk]);
        }
    } else {
        int mks[KMAX];
#pragma unroll
        for (int kk = 0; kk < KMAX; ++kk) mks[kk] = __shfl(m_final, kk);
        float g[KMAX];
#pragma unroll
        for (int kk = 0; kk < KMAX; ++kk)
            g[kk] = __half2float(ub[(size_t)mks[kk] * O + lane]);
#pragma unroll
        for (int kk = 0; kk < KMAX; ++kk) {
            if (kk < k) {
                gs += g[kk]; gs2 += g[kk] * g[kk];
                gmax = fmaxf(gmax, g[kk]); gmin = fminf(gmin, g[kk]);
            }
        }
    }
    float fk = (float)k;
    float s  = gs + fk * vv;
    float s2 = gs2 + 2.f * vv * gs + fk * vv * vv;
    ext[rowb * O + lane] = __halves2half2(__float2half(gmax + vv), __float2half(gmin + vv));
    rsum[t] = s; rsum2[t] = s2;
    __syncthreads();
    if (t < 64) {
        float a  = rsum[t] + rsum[t + 64] + rsum[t + 128] + rsum[t + 192];
        float a2 = rsum2[t] + rsum2[t + 64] + rsum2[t + 128] + rsum2[t + 192];
        float* sr = statsR + (size_t)(blockIdx.x & (NREP - 1)) * 128;
        atomicAdd(&sr[t], a);
        atomicAdd(&sr[64 + t], a2);
    }
}

// ---------- finalize BN affine (reduce NREP replicas) ----------
__global__ void ec_final(const float* __restrict__ statsR,
                         const float* __restrict__ gamma,
                         const float* __restrict__ beta,
                         const int* __restrict__ kptr,
                         float* __restrict__ scsh) {
    int o = threadIdx.x;                   // 64
    int k = *kptr;
    float s = 0.f, s2 = 0.f;
    for (int r = 0; r < NREP; ++r) {
        s  += statsR[r * 128 + o];
        s2 += statsR[r * 128 + 64 + o];
    }
    float M = (float)B * (float)N * (float)k;
    float mean = s / M;
    float var = s2 / M - mean * mean;
    var = fmaxf(var, 0.f);
    float sc = gamma[o] * rsqrtf(var + 1e-5f);
    float sh = beta[o] - mean * sc;
    scsh[o] = sc;
    scsh[64 + o] = sh;
}

// ---------- output: pick extreme by sc sign, BN + leaky, transpose ----------
__global__ __launch_bounds__(256) void ec_out(const __half2* __restrict__ ext,
                                              const float* __restrict__ scsh,
                                              float* __restrict__ out) {
    __shared__ float res[64][65];
    const int blk = blockIdx.x;            // B*N/64
    const int b = blk >> 6;
    const int n0 = (blk & 63) << 6;
    const int t = threadIdx.x;
    {
        const int o = t & 63, ni = t >> 6;
        float sc = scsh[o], sh = scsh[64 + o];
#pragma unroll 1
        for (int p = 0; p < 16; ++p) {
            int nl = ni * 16 + p;
            size_t a = ((size_t)b * N + n0 + nl) * O + o;
            __half2 e = ext[a];
            float y = (sc >= 0.f) ? __low2float(e) : __high2float(e);
            float z = sc * y + sh;
            res[nl][o] = (z >= 0.f) ? z : 0.2f * z;
        }
    }
    __syncthreads();
    {
        const int j = t & 63, oi = t >> 6;
#pragma unroll 1
        for (int p = 0; p < 16; ++p) {
            int o2 = oi * 16 + p;
            out[(size_t)b * O * N + (size_t)o2 * N + n0 + j] = res[j][o2];
        }
    }
}

extern "C" void kernel_launch(void* const* d_in, const int* in_sizes, int n_in,
                              void* d_out, int out_size, void* d_ws, size_t ws_size,
                              hipStream_t stream) {
    const float* x     = (const float*)d_in[0];
    const float* W     = (const float*)d_in[1];
    const float* gamma = (const float*)d_in[2];
    const float* beta  = (const float*)d_in[3];
    const int*   kptr  = (const int*)d_in[4];
    float* out = (float*)d_out;

    char* ws = (char*)d_ws;
    u32*    cand = (u32*)ws;    ws += (size_t)B * N * 64 * 8 * 4;  // 64 MB
    float*  xx   = (float*)ws;  ws += (size_t)B * N * 4;
    float*  xt   = (float*)ws;  ws += (size_t)B * N * C * 4;       // 8 MB
    u16*    xtb  = (u16*)ws;    ws += (size_t)B * N * C * 2;       // 4 MB
    __half* u_t  = (__half*)ws; ws += (size_t)B * N * O * 2;       // 4 MB
    __half* v_t  = (__half*)ws; ws += (size_t)B * N * O * 2;       // 4 MB
    __half2* ext = (__half2*)ws; ws += (size_t)B * N * O * 4;      // 8 MB
    float* statsR = (float*)ws; ws += (size_t)NREP * 128 * 4;      // 32 KB
    float* scsh  = (float*)ws;

    hipMemsetAsync(statsR, 0, NREP * 128 * 4, stream);
    ec_prep<<<B * N / 64, 256, 0, stream>>>(x, W, xx, xt, xtb, u_t, v_t);
    ec_gemm<<<dim3(N / 128, N / 128, B), 256, 0, stream>>>(xtb, xx, cand);
    ec_sel<<<dim3(N / 4, B), 256, 0, stream>>>(cand, xt, xx, u_t, v_t, kptr, ext, statsR);
    ec_final<<<1, 64, 0, stream>>>(statsR, gamma, beta, kptr, scsh);
    ec_out<<<B * N / 64, 256, 0, stream>>>(ext, scsh, out);
}

// Round 12
// 157.278 us; speedup vs baseline: 3.2972x; 1.0939x over previous
//
#include <hip/hip_runtime.h>
#include <hip/hip_fp16.h>
#include <float.h>

#define B 8
#define C 64
#define N 4096
#define O 64
#define KMAX 32
#define NREP 64   // stats replica buffers (atomic contention divider)

typedef unsigned short u16;
typedef unsigned int u32;
typedef unsigned long long u64;
typedef __attribute__((ext_vector_type(8))) u16 u16x8;
typedef __attribute__((ext_vector_type(8))) short bf16x8;
typedef __attribute__((ext_vector_type(4))) float f32x4;

__device__ __forceinline__ u16 f2bf(float f) {
    unsigned u = __builtin_bit_cast(unsigned, f);
    unsigned r = (u + 0x7FFFu + ((u >> 16) & 1)) >> 16;   // RTNE
    return (u16)r;
}

// ---------- fused prep: xt fp32, xtb bf16, xx, u/v fp16 ----------
__global__ __launch_bounds__(256) void ec_prep(const float* __restrict__ x,
                                               const float* __restrict__ W,
                                               float* __restrict__ xx,
                                               float* __restrict__ xt,
                                               u16* __restrict__ xtb,
                                               __half* __restrict__ u,
                                               __half* __restrict__ v) {
    __shared__ float xs[64][65];
    __shared__ float W1[C][64];
    __shared__ float Wd[C][64];
    __shared__ float rs[4][64];
    const int blk = blockIdx.x;            // B*N/64 = 512
    const int b = blk >> 6;
    const int n0 = (blk & 63) << 6;
    const int t = threadIdx.x;
#pragma unroll
    for (int p = 0; p < 16; ++p) {
        int q = t + 256 * p; int c = q >> 6, j = q & 63;
        xs[c][j] = x[(size_t)b * C * N + (size_t)c * N + n0 + j];
    }
#pragma unroll
    for (int p = 0; p < 16; ++p) {
        int q = t + 256 * p; int c = q >> 6, o = q & 63;
        float w1 = W[o * 128 + c];
        float w2 = W[o * 128 + 64 + c];
        W1[c][o] = w1; Wd[c][o] = w2 - w1;
    }
    __syncthreads();
    {
        const int j = t >> 2, g = t & 3;
        float vals[16]; float ss = 0.f;
#pragma unroll
        for (int i = 0; i < 16; ++i) { float f = xs[g * 16 + i][j]; vals[i] = f; ss += f * f; }
        rs[g][j] = ss;
        size_t rowb = ((size_t)b * N + n0 + j) * 64 + g * 16;
#pragma unroll
        for (int i = 0; i < 4; ++i) {
            float4 v4 = { vals[4 * i], vals[4 * i + 1], vals[4 * i + 2], vals[4 * i + 3] };
            *(float4*)&xt[rowb + 4 * i] = v4;
        }
        u16x8 h0, h1;
#pragma unroll
        for (int i = 0; i < 8; ++i) { h0[i] = f2bf(vals[i]); h1[i] = f2bf(vals[8 + i]); }
        *(u16x8*)&xtb[rowb] = h0;
        *(u16x8*)&xtb[rowb + 8] = h1;
    }
    // phase B: u/v projection, c-outer (W1/Wd read once per c, xs broadcast)
    {
        const int o = t & 63, ji = t >> 6;
        float su[16] = {}, sv[16] = {};
#pragma unroll 1
        for (int c = 0; c < C; ++c) {
            float w1 = W1[c][o];
            float wd = Wd[c][o];
#pragma unroll
            for (int p = 0; p < 16; ++p) {
                float xv = xs[c][ji + 4 * p];
                su[p] = fmaf(xv, w1, su[p]);
                sv[p] = fmaf(xv, wd, sv[p]);
            }
        }
#pragma unroll
        for (int p = 0; p < 16; ++p) {
            size_t base = ((size_t)b * N + n0 + ji + 4 * p) * O + o;
            u[base] = __float2half(su[p]);
            v[base] = __float2half(sv[p]);
        }
    }
    __syncthreads();
    if (t < 64) xx[(size_t)b * N + t + n0] = rs[0][t] + rs[1][t] + rs[2][t] + rs[3][t];
}

// ---------- in-register compare-exchange (descending: first arg keeps max) ----------
#define CXD(a, b) { u32 mx_ = max(a, b); b = min(a, b); a = mx_; }
#define CXA(a, b) { u32 mn_ = min(a, b); b = max(a, b); a = mn_; }
// bitonic sort-8 descending on named regs (24 CX)
#define BSORT8(e0,e1,e2,e3,e4,e5,e6,e7) { \
    CXD(e0,e1) CXA(e2,e3) CXD(e4,e5) CXA(e6,e7) \
    CXD(e0,e2) CXD(e1,e3) CXA(e4,e6) CXA(e5,e7) \
    CXD(e0,e1) CXD(e2,e3) CXA(e4,e5) CXA(e6,e7) \
    CXD(e0,e4) CXD(e1,e5) CXD(e2,e6) CXD(e3,e7) \
    CXD(e0,e2) CXD(e1,e3) CXD(e4,e6) CXD(e5,e7) \
    CXD(e0,e1) CXD(e2,e3) CXD(e4,e5) CXD(e6,e7) }
// merge sorted-8 e into sorted-8 t keeping top-8 (8 max + 12 CX clean)
#define MERGETOP8(t0,t1,t2,t3,t4,t5,t6,t7, e0,e1,e2,e3,e4,e5,e6,e7) { \
    t0 = max(t0, e7); t1 = max(t1, e6); t2 = max(t2, e5); t3 = max(t3, e4); \
    t4 = max(t4, e3); t5 = max(t5, e2); t6 = max(t6, e1); t7 = max(t7, e0); \
    CXD(t0,t4) CXD(t1,t5) CXD(t2,t6) CXD(t3,t7) \
    CXD(t0,t2) CXD(t1,t3) CXD(t4,t6) CXD(t5,t7) \
    CXD(t0,t1) CXD(t2,t3) CXD(t4,t5) CXD(t6,t7) }

// ---------- MFMA distance + fused per-(row,128-col-chunk) top-8 ----------
// Key: dvp = 2*acc - xm + 2560 in (2230,2780) -> single binade [2048,4096)
// -> (u16)(bits>>7) is monotone in d, granularity 2^-5.
// cand[((b*N+row)*32 + chunk)*8 + s] : packed u32 = (key16<<12)|(4095-m)
__global__ __launch_bounds__(256) void ec_gemm(const u16* __restrict__ xtb,
                                               const float* __restrict__ xx,
                                               u32* __restrict__ cand) {
    __shared__ u16 lds[18432 + 8];
    const int t = threadIdx.x;
    const int m0 = blockIdx.x * 128, n0 = blockIdx.y * 128;
    const int b = blockIdx.z;
    const u16* xa = xtb + (size_t)b * N * 64;
#pragma unroll
    for (int p = 0; p < 4; ++p) {
        int q = t + 256 * p;
        int row = q >> 3, ch = q & 7;
        int by = (row * 128 + ch * 16) ^ ((row & 7) << 4);
        *(u16x8*)((char*)lds + by) = *(const u16x8*)&xa[(size_t)(n0 + row) * 64 + ch * 8];
        *(u16x8*)((char*)lds + 16384 + by) = *(const u16x8*)&xa[(size_t)(m0 + row) * 64 + ch * 8];
    }
    __syncthreads();
    const int w = t >> 6, lane = t & 63;
    const int wr = w >> 1, wc = w & 1;
    const int fr = lane & 15, fg = lane >> 4;
    f32x4 acc[4][4] = {};
#pragma unroll
    for (int ks = 0; ks < 2; ++ks) {
        bf16x8 af[4], bg[4];
#pragma unroll
        for (int fi = 0; fi < 4; ++fi) {
            int rowA = 64 * wr + 16 * fi + fr;
            int byA = (rowA * 128 + ks * 64 + fg * 16) ^ ((rowA & 7) << 4);
            af[fi] = *(const bf16x8*)((const char*)lds + byA);
            int rowB = 64 * wc + 16 * fi + fr;
            int byB = (rowB * 128 + ks * 64 + fg * 16) ^ ((rowB & 7) << 4);
            bg[fi] = *(const bf16x8*)((const char*)lds + 16384 + byB);
        }
#pragma unroll
        for (int fi = 0; fi < 4; ++fi)
#pragma unroll
            for (int fj = 0; fj < 4; ++fj)
                acc[fi][fj] = __builtin_amdgcn_mfma_f32_16x16x32_bf16(af[fi], bg[fj], acc[fi][fj], 0, 0, 0);
    }
    float xmK[4];
#pragma unroll
    for (int fj = 0; fj < 4; ++fj)
        xmK[fj] = 2560.f - xx[(size_t)b * N + m0 + 64 * wc + 16 * fj + fr];
    __syncthreads();                        // staging LDS dead; reuse for epilogue
    u16* ep = lds + w * 4608;               // 64 rows x stride 72 u16 (144 B)
#pragma unroll
    for (int fi = 0; fi < 4; ++fi)
#pragma unroll
        for (int fj = 0; fj < 4; ++fj)
#pragma unroll
            for (int r = 0; r < 4; ++r) {
                float dvp = fmaf(2.f, acc[fi][fj][r], xmK[fj]);   // in (2230,2780)
                u32 bits = __builtin_bit_cast(u32, dvp);
                int row = 16 * fi + fg * 4 + r, col = 16 * fj + fr;
                ep[row * 72 + col] = (u16)(bits >> 7);            // monotone key
            }
    __syncthreads();
    // per-lane: row = lane; sorting-network top-8 over own 64 cols
    const u16* myrow = lds + w * 4608 + lane * 72;
    const int mbase = m0 + (wc << 6);
    const u32 invb = (u32)(4095 - mbase);   // wave-uniform
    u32 t0, t1, t2, t3, t4, t5, t6, t7;
    {
        u16x8 q = *(const u16x8*)&myrow[0];
        t0 = ((u32)q[0] << 12) | (invb - 0); t1 = ((u32)q[1] << 12) | (invb - 1);
        t2 = ((u32)q[2] << 12) | (invb - 2); t3 = ((u32)q[3] << 12) | (invb - 3);
        t4 = ((u32)q[4] << 12) | (invb - 4); t5 = ((u32)q[5] << 12) | (invb - 5);
        t6 = ((u32)q[6] << 12) | (invb - 6); t7 = ((u32)q[7] << 12) | (invb - 7);
        BSORT8(t0, t1, t2, t3, t4, t5, t6, t7)
    }
#pragma unroll
    for (int g = 1; g < 8; ++g) {
        u16x8 q = *(const u16x8*)&myrow[g * 8];
        const u32 inv0 = invb - (u32)(g * 8);  // wave-uniform
        u32 e0 = ((u32)q[0] << 12) | (inv0 - 0), e1 = ((u32)q[1] << 12) | (inv0 - 1);
        u32 e2 = ((u32)q[2] << 12) | (inv0 - 2), e3 = ((u32)q[3] << 12) | (inv0 - 3);
        u32 e4 = ((u32)q[4] << 12) | (inv0 - 4), e5 = ((u32)q[5] << 12) | (inv0 - 5);
        u32 e6 = ((u32)q[6] << 12) | (inv0 - 6), e7 = ((u32)q[7] << 12) | (inv0 - 7);
        BSORT8(e0, e1, e2, e3, e4, e5, e6, e7)
        MERGETOP8(t0, t1, t2, t3, t4, t5, t6, t7, e0, e1, e2, e3, e4, e5, e6, e7)
    }
    // cross-warp merge: wc=1 half into wc=0 half -> top-8 per 128-col chunk
    __syncthreads();                        // all myrow reads done
    u32* mbuf = (u32*)lds;                  // 4 KB reuse
    if (wc) {
        u32* mp = mbuf + (size_t)((wr << 6) | lane) * 8;
        uint4 w0 = { t0, t1, t2, t3 }, w1 = { t4, t5, t6, t7 };
        *(uint4*)mp = w0;
        *(uint4*)(mp + 4) = w1;
    }
    __syncthreads();
    if (!wc) {
        const u32* mp = mbuf + (size_t)((wr << 6) | lane) * 8;
        uint4 b0 = *(const uint4*)mp, b1 = *(const uint4*)(mp + 4);
        u32 e0 = b0.x, e1 = b0.y, e2 = b0.z, e3 = b0.w;
        u32 e4 = b1.x, e5 = b1.y, e6 = b1.z, e7 = b1.w;
        MERGETOP8(t0, t1, t2, t3, t4, t5, t6, t7, e0, e1, e2, e3, e4, e5, e6, e7)
        const int row_g = n0 + 64 * wr + lane;
        u32* cp = cand + (((size_t)b * N + row_g) * 32 + blockIdx.x) * 8;
        uint4 w0 = { t0, t1, t2, t3 }, w1 = { t4, t5, t6, t7 };
        *(uint4*)cp = w0;
        *(uint4*)(cp + 4) = w1;
    }
}

// ---------- distributed merge-tree helpers (4 keys/lane) ----------
#define CX4(i, j) { u32 mn_ = min(c[i], c[j]); c[i] = max(c[i], c[j]); c[j] = mn_; }
#define CLEAN4IN() { CX4(0,2) CX4(1,3) CX4(0,1) CX4(2,3) }
#define DSTEP(xorm, bit) { \
    u32 pr_[4]; \
    _Pragma("unroll") for (int i_ = 0; i_ < 4; ++i_) pr_[i_] = __shfl_xor(c[i_], xorm); \
    bool km_ = (lane & (bit)) == 0; \
    _Pragma("unroll") for (int i_ = 0; i_ < 4; ++i_) \
        c[i_] = km_ ? max(c[i_], pr_[i_]) : min(c[i_], pr_[i_]); }

// ---------- sel: merge-tree top-32 -> exact rescore -> sort-32 -> stats ----------
__global__ __launch_bounds__(256) void ec_sel(const u32* __restrict__ cand,
                                              const float* __restrict__ xt,
                                              const float* __restrict__ xx,
                                              const __half* __restrict__ u,
                                              const __half* __restrict__ v,
                                              const int* __restrict__ kptr,
                                              __half2* __restrict__ ext,
                                              float* __restrict__ statsR) {
    __shared__ float sxn[4][64];
    __shared__ int scand[4][32];
    __shared__ float rsum[256], rsum2[256];
    const int t = threadIdx.x, w = t >> 6, lane = t & 63;
    const int b = blockIdx.y;
    const int n = blockIdx.x * 4 + w;
    const int k = *kptr;

    // lane pair (2c,2c+1) holds chunk c's sorted-8; rank = 4*(lane&1)+reg
    const u32* cp = cand + (((size_t)b * N + n) * 32 + (lane >> 1)) * 8 + (lane & 1) * 4;
    uint4 a0 = *(const uint4*)cp;
    u32 c[4] = { a0.x, a0.y, a0.z, a0.w };

    // L1 (xor2): chunk pairs -> sorted-16 over 4 lanes
    {
        u32 pr[4];
#pragma unroll
        for (int i = 0; i < 4; ++i) pr[i] = __shfl_xor(c[3 - i], 3);
        bool lo = (lane & 2) == 0;
#pragma unroll
        for (int i = 0; i < 4; ++i) {
            u32 mx = max(c[i], pr[i]), mn = min(c[i], pr[i]);
            c[i] = lo ? mx : mn;
        }
        DSTEP(1, 1)
        CLEAN4IN()
    }
    // L2 (xor4): -> sorted-32 over 8 lanes
    {
        u32 pr[4];
#pragma unroll
        for (int i = 0; i < 4; ++i) pr[i] = __shfl_xor(c[3 - i], 7);
        bool lo = (lane & 4) == 0;
#pragma unroll
        for (int i = 0; i < 4; ++i) {
            u32 mx = max(c[i], pr[i]), mn = min(c[i], pr[i]);
            c[i] = lo ? mx : mn;
        }
        DSTEP(2, 2) DSTEP(1, 1)
        CLEAN4IN()
    }
    // L3-5: top-32 halver + bitonic-32 clean (8-lane groups 8/16/32 apart)
#define MT32(mask) { \
        u32 pr_[4]; \
        _Pragma("unroll") for (int i_ = 0; i_ < 4; ++i_) pr_[i_] = __shfl_xor(c[3 - i_], mask); \
        _Pragma("unroll") for (int i_ = 0; i_ < 4; ++i_) c[i_] = max(c[i_], pr_[i_]); \
        DSTEP(4, 4) DSTEP(2, 2) DSTEP(1, 1) CLEAN4IN() }
    MT32(15)
    MT32(23)
    MT32(39)
#undef MT32

    // lanes 0-7 hold global top-32 sorted desc: rank = 4*lane + reg
    if (lane < 8) {
#pragma unroll
        for (int i = 0; i < 4; ++i) scand[w][lane * 4 + i] = 4095 - (int)(c[i] & 0xFFFu);
    }
    sxn[w][lane] = xt[((size_t)b * N + n) * 64 + lane];
    __syncthreads();

    // exact fp32 rescore: lane = (candidate jc, c-half h)
    const float* xt_ = xt + (size_t)b * N * 64;
    const int jc = lane & 31, h = lane >> 5;
    const int mj = scand[w][jc];
    const float* xr = xt_ + (size_t)mj * 64 + h * 32;
    float acc = 0.f;
#pragma unroll
    for (int q8 = 0; q8 < 8; ++q8) {
        float4 g4 = *(const float4*)&xr[q8 * 4];
        float4 xn4 = *(const float4*)&sxn[w][h * 32 + q8 * 4];
        acc += g4.x * xn4.x + g4.y * xn4.y + g4.z * xn4.z + g4.w * xn4.w;
    }
    acc += __shfl_xor(acc, 32);
    float ex = 2.f * acc - xx[(size_t)b * N + mj];
    unsigned fu = __builtin_bit_cast(unsigned, ex);
    unsigned sf = fu ^ (unsigned)(((int)fu >> 31) | 0x80000000);
    u64 key = ((u64)sf << 12) | (u64)(4095 - mj);
    if (h) key = 0;                        // duplicate copy lives in lanes 32..63

    // descending bitonic sort of 32 u64 keys (lanes 0..31; halves isolated)
#pragma unroll
    for (int ls = 1; ls <= 5; ++ls) {
        const int s = 1 << ls;
        const bool lb = (lane & s) == 0;
#pragma unroll
        for (int dd = s >> 1; dd >= 1; dd >>= 1) {
            const bool km = ((lane & dd) == 0) == lb;
            u64 pv = __shfl_xor(key, dd);
            u64 mn = key < pv ? key : pv;
            u64 mx = key < pv ? pv : key;
            key = km ? mx : mn;
        }
    }
    int m_final = 4095 - (int)(key & 0xFFFu);   // lane r (<32) = r-th best exact

    // fused BN stats gather: lane = o
    const __half* ub = u + (size_t)b * N * O;
    size_t rowb = (size_t)b * N + n;
    float vv = __half2float(v[rowb * O + lane]);
    float gmax = -FLT_MAX, gmin = FLT_MAX, gs = 0.f, gs2 = 0.f;
    if (k == 20) {
        int mks[20];
#pragma unroll
        for (int kk = 0; kk < 20; ++kk) mks[kk] = __shfl(m_final, kk);
        float g[20];
#pragma unroll
        for (int kk = 0; kk < 20; ++kk)
            g[kk] = __half2float(ub[(size_t)mks[kk] * O + lane]);
#pragma unroll
        for (int kk = 0; kk < 20; ++kk) {
            gs += g[kk]; gs2 += g[kk] * g[kk];
            gmax = fmaxf(gmax, g[kk]); gmin = fminf(gmin, g[kk]);
        }
    } else {
        int mks[KMAX];
#pragma unroll
        for (int kk = 0; kk < KMAX; ++kk) mks[kk] = __shfl(m_final, kk);
        float g[KMAX];
#pragma unroll
        for (int kk = 0; kk < KMAX; ++kk)
            g[kk] = __half2float(ub[(size_t)mks[kk] * O + lane]);
#pragma unroll
        for (int kk = 0; kk < KMAX; ++kk) {
            if (kk < k) {
                gs += g[kk]; gs2 += g[kk] * g[kk];
                gmax = fmaxf(gmax, g[kk]); gmin = fminf(gmin, g[kk]);
            }
        }
    }
    float fk = (float)k;
    float s  = gs + fk * vv;
    float s2 = gs2 + 2.f * vv * gs + fk * vv * vv;
    ext[rowb * O + lane] = __halves2half2(__float2half(gmax + vv), __float2half(gmin + vv));
    rsum[t] = s; rsum2[t] = s2;
    __syncthreads();
    if (t < 64) {
        float a  = rsum[t] + rsum[t + 64] + rsum[t + 128] + rsum[t + 192];
        float a2 = rsum2[t] + rsum2[t + 64] + rsum2[t + 128] + rsum2[t + 192];
        float* sr = statsR + (size_t)(blockIdx.x & (NREP - 1)) * 128;
        atomicAdd(&sr[t], a);
        atomicAdd(&sr[64 + t], a2);
    }
}

// ---------- finalize BN affine (reduce NREP replicas) ----------
__global__ void ec_final(const float* __restrict__ statsR,
                         const float* __restrict__ gamma,
                         const float* __restrict__ beta,
                         const int* __restrict__ kptr,
                         float* __restrict__ scsh) {
    int o = threadIdx.x;                   // 64
    int k = *kptr;
    float s = 0.f, s2 = 0.f;
    for (int r = 0; r < NREP; ++r) {
        s  += statsR[r * 128 + o];
        s2 += statsR[r * 128 + 64 + o];
    }
    float M = (float)B * (float)N * (float)k;
    float mean = s / M;
    float var = s2 / M - mean * mean;
    var = fmaxf(var, 0.f);
    float sc = gamma[o] * rsqrtf(var + 1e-5f);
    float sh = beta[o] - mean * sc;
    scsh[o] = sc;
    scsh[64 + o] = sh;
}

// ---------- output: pick extreme by sc sign, BN + leaky, transpose ----------
__global__ __launch_bounds__(256) void ec_out(const __half2* __restrict__ ext,
                                              const float* __restrict__ scsh,
                                              float* __restrict__ out) {
    __shared__ float res[64][65];
    const int blk = blockIdx.x;            // B*N/64
    const int b = blk >> 6;
    const int n0 = (blk & 63) << 6;
    const int t = threadIdx.x;
    {
        const int o = t & 63, ni = t >> 6;
        float sc = scsh[o], sh = scsh[64 + o];
#pragma unroll 1
        for (int p = 0; p < 16; ++p) {
            int nl = ni * 16 + p;
            size_t a = ((size_t)b * N + n0 + nl) * O + o;
            __half2 e = ext[a];
            float y = (sc >= 0.f) ? __low2float(e) : __high2float(e);
            float z = sc * y + sh;
            res[nl][o] = (z >= 0.f) ? z : 0.2f * z;
        }
    }
    __syncthreads();
    {
        const int j = t & 63, oi = t >> 6;
#pragma unroll 1
        for (int p = 0; p < 16; ++p) {
            int o2 = oi * 16 + p;
            out[(size_t)b * O * N + (size_t)o2 * N + n0 + j] = res[j][o2];
        }
    }
}

extern "C" void kernel_launch(void* const* d_in, const int* in_sizes, int n_in,
                              void* d_out, int out_size, void* d_ws, size_t ws_size,
                              hipStream_t stream) {
    const float* x     = (const float*)d_in[0];
    const float* W     = (const float*)d_in[1];
    const float* gamma = (const float*)d_in[2];
    const float* beta  = (const float*)d_in[3];
    const int*   kptr  = (const int*)d_in[4];
    float* out = (float*)d_out;

    char* ws = (char*)d_ws;
    u32*    cand = (u32*)ws;    ws += (size_t)B * N * 32 * 8 * 4;  // 32 MB
    float*  xx   = (float*)ws;  ws += (size_t)B * N * 4;
    float*  xt   = (float*)ws;  ws += (size_t)B * N * C * 4;       // 8 MB
    u16*    xtb  = (u16*)ws;    ws += (size_t)B * N * C * 2;       // 4 MB
    __half* u_t  = (__half*)ws; ws += (size_t)B * N * O * 2;       // 4 MB
    __half* v_t  = (__half*)ws; ws += (size_t)B * N * O * 2;       // 4 MB
    __half2* ext = (__half2*)ws; ws += (size_t)B * N * O * 4;      // 8 MB
    float* statsR = (float*)ws; ws += (size_t)NREP * 128 * 4;      // 32 KB
    float* scsh  = (float*)ws;

    hipMemsetAsync(statsR, 0, NREP * 128 * 4, stream);
    ec_prep<<<B * N / 64, 256, 0, stream>>>(x, W, xx, xt, xtb, u_t, v_t);
    ec_gemm<<<dim3(N / 128, N / 128, B), 256, 0, stream>>>(xtb, xx, cand);
    ec_sel<<<dim3(N / 4, B), 256, 0, stream>>>(cand, xt, xx, u_t, v_t, kptr, ext, statsR);
    ec_final<<<1, 64, 0, stream>>>(statsR, gamma, beta, kptr, scsh);
    ec_out<<<B * N / 64, 256, 0, stream>>>(ext, scsh, out);
}

// Round 13
// 146.982 us; speedup vs baseline: 3.5282x; 1.0700x over previous
//
#include <hip/hip_runtime.h>
#include <hip/hip_fp16.h>
#include <float.h>

#define B 8
#define C 64
#define N 4096
#define O 64
#define KMAX 32
#define NREP 64   // stats replica buffers (atomic contention divider)

typedef unsigned short u16;
typedef unsigned int u32;
typedef unsigned long long u64;
typedef __attribute__((ext_vector_type(8))) u16 u16x8;
typedef __attribute__((ext_vector_type(8))) short bf16x8;
typedef __attribute__((ext_vector_type(4))) float f32x4;

__device__ __forceinline__ u16 f2bf(float f) {
    unsigned u = __builtin_bit_cast(unsigned, f);
    unsigned r = (u + 0x7FFFu + ((u >> 16) & 1)) >> 16;   // RTNE
    return (u16)r;
}

// ---------- fused prep: xt fp32, xtb bf16, xx, u/v fp16 ----------
// 32-col tiles (1024 blocks), coalesced W staging, fp16-packed W in LDS.
__global__ __launch_bounds__(256) void ec_prep(const float* __restrict__ x,
                                               const float* __restrict__ W,
                                               float* __restrict__ xx,
                                               float* __restrict__ xt,
                                               u16* __restrict__ xtb,
                                               __half* __restrict__ u,
                                               __half* __restrict__ v) {
    __shared__ float xs[64][33];           // 8448 B
    __shared__ __half2 Wp[C][65];          // 16640 B (pad -> conflict-free)
    __shared__ float rs[8][32];            // 1024 B
    const int blk = blockIdx.x;            // B*N/32 = 1024
    const int b = blk >> 7;
    const int n0 = (blk & 127) << 5;
    const int t = threadIdx.x;
#pragma unroll
    for (int p = 0; p < 8; ++p) {
        int q = t + 256 * p; int c = q >> 5, j = q & 31;
        xs[c][j] = x[(size_t)b * C * N + (size_t)c * N + n0 + j];
    }
#pragma unroll
    for (int p = 0; p < 16; ++p) {
        int q = t + 256 * p; int o = q >> 6, c = q & 63;   // lanes: consecutive c
        float w1 = W[o * 128 + c];
        float w2 = W[o * 128 + 64 + c];
        Wp[c][o] = __floats2half2_rn(w1, w2 - w1);
    }
    __syncthreads();
    // phase A: transpose out + norms (thread = (j, c-eighth))
    {
        const int j = t >> 3, g = t & 7;
        float vals[8]; float ss = 0.f;
#pragma unroll
        for (int i = 0; i < 8; ++i) { float f = xs[g * 8 + i][j]; vals[i] = f; ss += f * f; }
        rs[g][j] = ss;
        size_t rowb = ((size_t)b * N + n0 + j) * 64 + g * 8;
        float4 v0 = { vals[0], vals[1], vals[2], vals[3] };
        float4 v1 = { vals[4], vals[5], vals[6], vals[7] };
        *(float4*)&xt[rowb] = v0;
        *(float4*)&xt[rowb + 4] = v1;
        u16x8 h0;
#pragma unroll
        for (int i = 0; i < 8; ++i) h0[i] = f2bf(vals[i]);
        *(u16x8*)&xtb[rowb] = h0;
    }
    // phase B: u/v projection, c-outer
    {
        const int o = t & 63, ji = t >> 6;
        float su[8] = {}, sv[8] = {};
#pragma unroll 1
        for (int c = 0; c < C; ++c) {
            __half2 wp = Wp[c][o];
            float w1 = __low2float(wp), wd = __high2float(wp);
#pragma unroll
            for (int p = 0; p < 8; ++p) {
                float xv = xs[c][ji + 4 * p];
                su[p] = fmaf(xv, w1, su[p]);
                sv[p] = fmaf(xv, wd, sv[p]);
            }
        }
#pragma unroll
        for (int p = 0; p < 8; ++p) {
            size_t base = ((size_t)b * N + n0 + ji + 4 * p) * O + o;
            u[base] = __float2half(su[p]);
            v[base] = __float2half(sv[p]);
        }
    }
    __syncthreads();
    if (t < 32) {
        float a = 0.f;
#pragma unroll
        for (int g = 0; g < 8; ++g) a += rs[g][t];
        xx[(size_t)b * N + n0 + t] = a;
    }
}

// ---------- in-register compare-exchange (descending: first arg keeps max) ----------
#define CXD(a, b) { u32 mx_ = max(a, b); b = min(a, b); a = mx_; }
// Batcher optimal 19-comparator sort-8, descending
#define BSORT8(e0,e1,e2,e3,e4,e5,e6,e7) { \
    CXD(e0,e1) CXD(e2,e3) CXD(e4,e5) CXD(e6,e7) \
    CXD(e0,e2) CXD(e1,e3) CXD(e4,e6) CXD(e5,e7) \
    CXD(e1,e2) CXD(e5,e6) CXD(e0,e4) CXD(e3,e7) \
    CXD(e1,e5) CXD(e2,e6) \
    CXD(e1,e4) CXD(e3,e6) \
    CXD(e2,e4) CXD(e3,e5) \
    CXD(e3,e4) }
// merge sorted-8 e into sorted-8 t keeping top-8 (8 max + 12 CX clean)
#define MERGETOP8(t0,t1,t2,t3,t4,t5,t6,t7, e0,e1,e2,e3,e4,e5,e6,e7) { \
    t0 = max(t0, e7); t1 = max(t1, e6); t2 = max(t2, e5); t3 = max(t3, e4); \
    t4 = max(t4, e3); t5 = max(t5, e2); t6 = max(t6, e1); t7 = max(t7, e0); \
    CXD(t0,t4) CXD(t1,t5) CXD(t2,t6) CXD(t3,t7) \
    CXD(t0,t2) CXD(t1,t3) CXD(t4,t6) CXD(t5,t7) \
    CXD(t0,t1) CXD(t2,t3) CXD(t4,t5) CXD(t6,t7) }

// ---------- MFMA distance + fused per-(row,128-col-chunk) top-8 ----------
// Key: dvp = 2*acc - xm + 2560 in (2230,2780) -> single binade [2048,4096)
// -> (u16)(bits>>7) is monotone in d, granularity 2^-5.
// cand[((b*N+row)*32 + chunk)*8 + s] : packed u32 = (key16<<12)|(4095-m)
__global__ __launch_bounds__(256) void ec_gemm(const u16* __restrict__ xtb,
                                               const float* __restrict__ xx,
                                               u32* __restrict__ cand) {
    __shared__ u16 lds[18432 + 8];
    const int t = threadIdx.x;
    const int m0 = blockIdx.x * 128, n0 = blockIdx.y * 128;
    const int b = blockIdx.z;
    const u16* xa = xtb + (size_t)b * N * 64;
#pragma unroll
    for (int p = 0; p < 4; ++p) {
        int q = t + 256 * p;
        int row = q >> 3, ch = q & 7;
        int by = (row * 128 + ch * 16) ^ ((row & 7) << 4);
        *(u16x8*)((char*)lds + by) = *(const u16x8*)&xa[(size_t)(n0 + row) * 64 + ch * 8];
        *(u16x8*)((char*)lds + 16384 + by) = *(const u16x8*)&xa[(size_t)(m0 + row) * 64 + ch * 8];
    }
    __syncthreads();
    const int w = t >> 6, lane = t & 63;
    const int wr = w >> 1, wc = w & 1;
    const int fr = lane & 15, fg = lane >> 4;
    f32x4 acc[4][4] = {};
#pragma unroll
    for (int ks = 0; ks < 2; ++ks) {
        bf16x8 af[4], bg[4];
#pragma unroll
        for (int fi = 0; fi < 4; ++fi) {
            int rowA = 64 * wr + 16 * fi + fr;
            int byA = (rowA * 128 + ks * 64 + fg * 16) ^ ((rowA & 7) << 4);
            af[fi] = *(const bf16x8*)((const char*)lds + byA);
            int rowB = 64 * wc + 16 * fi + fr;
            int byB = (rowB * 128 + ks * 64 + fg * 16) ^ ((rowB & 7) << 4);
            bg[fi] = *(const bf16x8*)((const char*)lds + 16384 + byB);
        }
#pragma unroll
        for (int fi = 0; fi < 4; ++fi)
#pragma unroll
            for (int fj = 0; fj < 4; ++fj)
                acc[fi][fj] = __builtin_amdgcn_mfma_f32_16x16x32_bf16(af[fi], bg[fj], acc[fi][fj], 0, 0, 0);
    }
    float xmK[4];
#pragma unroll
    for (int fj = 0; fj < 4; ++fj)
        xmK[fj] = 2560.f - xx[(size_t)b * N + m0 + 64 * wc + 16 * fj + fr];
    __syncthreads();                        // staging LDS dead; reuse for epilogue
    u16* ep = lds + w * 4608;               // 64 rows x stride 72 u16 (144 B)
#pragma unroll
    for (int fi = 0; fi < 4; ++fi)
#pragma unroll
        for (int fj = 0; fj < 4; ++fj)
#pragma unroll
            for (int r = 0; r < 4; ++r) {
                float dvp = fmaf(2.f, acc[fi][fj][r], xmK[fj]);   // in (2230,2780)
                u32 bits = __builtin_bit_cast(u32, dvp);
                int row = 16 * fi + fg * 4 + r, col = 16 * fj + fr;
                ep[row * 72 + col] = (u16)(bits >> 7);            // monotone key
            }
    __syncthreads();
    // per-lane: row = lane; sorting-network top-8 over own 64 cols
    const u16* myrow = lds + w * 4608 + lane * 72;
    const int mbase = m0 + (wc << 6);
    const u32 invb = (u32)(4095 - mbase);   // wave-uniform
    u32 t0, t1, t2, t3, t4, t5, t6, t7;
    {
        u16x8 q = *(const u16x8*)&myrow[0];
        t0 = ((u32)q[0] << 12) | (invb - 0); t1 = ((u32)q[1] << 12) | (invb - 1);
        t2 = ((u32)q[2] << 12) | (invb - 2); t3 = ((u32)q[3] << 12) | (invb - 3);
        t4 = ((u32)q[4] << 12) | (invb - 4); t5 = ((u32)q[5] << 12) | (invb - 5);
        t6 = ((u32)q[6] << 12) | (invb - 6); t7 = ((u32)q[7] << 12) | (invb - 7);
        BSORT8(t0, t1, t2, t3, t4, t5, t6, t7)
    }
#pragma unroll
    for (int g = 1; g < 8; ++g) {
        u16x8 q = *(const u16x8*)&myrow[g * 8];
        const u32 inv0 = invb - (u32)(g * 8);  // wave-uniform
        u32 e0 = ((u32)q[0] << 12) | (inv0 - 0), e1 = ((u32)q[1] << 12) | (inv0 - 1);
        u32 e2 = ((u32)q[2] << 12) | (inv0 - 2), e3 = ((u32)q[3] << 12) | (inv0 - 3);
        u32 e4 = ((u32)q[4] << 12) | (inv0 - 4), e5 = ((u32)q[5] << 12) | (inv0 - 5);
        u32 e6 = ((u32)q[6] << 12) | (inv0 - 6), e7 = ((u32)q[7] << 12) | (inv0 - 7);
        BSORT8(e0, e1, e2, e3, e4, e5, e6, e7)
        MERGETOP8(t0, t1, t2, t3, t4, t5, t6, t7, e0, e1, e2, e3, e4, e5, e6, e7)
    }
    // cross-warp merge: wc=1 half into wc=0 half -> top-8 per 128-col chunk
    __syncthreads();                        // all myrow reads done
    u32* mbuf = (u32*)lds;                  // 4 KB reuse
    if (wc) {
        u32* mp = mbuf + (size_t)((wr << 6) | lane) * 8;
        uint4 w0 = { t0, t1, t2, t3 }, w1 = { t4, t5, t6, t7 };
        *(uint4*)mp = w0;
        *(uint4*)(mp + 4) = w1;
    }
    __syncthreads();
    if (!wc) {
        const u32* mp = mbuf + (size_t)((wr << 6) | lane) * 8;
        uint4 b0 = *(const uint4*)mp, b1 = *(const uint4*)(mp + 4);
        u32 e0 = b0.x, e1 = b0.y, e2 = b0.z, e3 = b0.w;
        u32 e4 = b1.x, e5 = b1.y, e6 = b1.z, e7 = b1.w;
        MERGETOP8(t0, t1, t2, t3, t4, t5, t6, t7, e0, e1, e2, e3, e4, e5, e6, e7)
        const int row_g = n0 + 64 * wr + lane;
        u32* cp = cand + (((size_t)b * N + row_g) * 32 + blockIdx.x) * 8;
        uint4 w0 = { t0, t1, t2, t3 }, w1 = { t4, t5, t6, t7 };
        *(uint4*)cp = w0;
        *(uint4*)(cp + 4) = w1;
    }
}

// ---------- distributed merge-tree helpers (4 keys/lane) ----------
#define CX4(i, j) { u32 mn_ = min(c[i], c[j]); c[i] = max(c[i], c[j]); c[j] = mn_; }
#define CLEAN4IN() { CX4(0,2) CX4(1,3) CX4(0,1) CX4(2,3) }
#define DSTEP(xorm, bit) { \
    u32 pr_[4]; \
    _Pragma("unroll") for (int i_ = 0; i_ < 4; ++i_) pr_[i_] = __shfl_xor(c[i_], xorm); \
    bool km_ = (lane & (bit)) == 0; \
    _Pragma("unroll") for (int i_ = 0; i_ < 4; ++i_) \
        c[i_] = km_ ? max(c[i_], pr_[i_]) : min(c[i_], pr_[i_]); }

// ---------- sel: merge-tree top-32 -> exact rescore -> sort-32 -> stats ----------
__global__ __launch_bounds__(256) void ec_sel(const u32* __restrict__ cand,
                                              const float* __restrict__ xt,
                                              const float* __restrict__ xx,
                                              const __half* __restrict__ u,
                                              const __half* __restrict__ v,
                                              const int* __restrict__ kptr,
                                              __half2* __restrict__ ext,
                                              float* __restrict__ statsR) {
    __shared__ float sxn[4][64];
    __shared__ int scand[4][32];
    __shared__ float rsum[256], rsum2[256];
    const int t = threadIdx.x, w = t >> 6, lane = t & 63;
    const int b = blockIdx.y;
    const int n = blockIdx.x * 4 + w;
    const int k = *kptr;

    // lane pair (2c,2c+1) holds chunk c's sorted-8; rank = 4*(lane&1)+reg
    const u32* cp = cand + (((size_t)b * N + n) * 32 + (lane >> 1)) * 8 + (lane & 1) * 4;
    uint4 a0 = *(const uint4*)cp;
    u32 c[4] = { a0.x, a0.y, a0.z, a0.w };

    // L1 (xor2): chunk pairs -> sorted-16 over 4 lanes
    {
        u32 pr[4];
#pragma unroll
        for (int i = 0; i < 4; ++i) pr[i] = __shfl_xor(c[3 - i], 3);
        bool lo = (lane & 2) == 0;
#pragma unroll
        for (int i = 0; i < 4; ++i) {
            u32 mx = max(c[i], pr[i]), mn = min(c[i], pr[i]);
            c[i] = lo ? mx : mn;
        }
        DSTEP(1, 1)
        CLEAN4IN()
    }
    // L2 (xor4): -> sorted-32 over 8 lanes
    {
        u32 pr[4];
#pragma unroll
        for (int i = 0; i < 4; ++i) pr[i] = __shfl_xor(c[3 - i], 7);
        bool lo = (lane & 4) == 0;
#pragma unroll
        for (int i = 0; i < 4; ++i) {
            u32 mx = max(c[i], pr[i]), mn = min(c[i], pr[i]);
            c[i] = lo ? mx : mn;
        }
        DSTEP(2, 2) DSTEP(1, 1)
        CLEAN4IN()
    }
    // L3-5: top-32 halver + bitonic-32 clean (8-lane groups 8/16/32 apart)
#define MT32(mask) { \
        u32 pr_[4]; \
        _Pragma("unroll") for (int i_ = 0; i_ < 4; ++i_) pr_[i_] = __shfl_xor(c[3 - i_], mask); \
        _Pragma("unroll") for (int i_ = 0; i_ < 4; ++i_) c[i_] = max(c[i_], pr_[i_]); \
        DSTEP(4, 4) DSTEP(2, 2) DSTEP(1, 1) CLEAN4IN() }
    MT32(15)
    MT32(23)
    MT32(39)
#undef MT32

    // lanes 0-7 hold global top-32 sorted desc: rank = 4*lane + reg
    if (lane < 8) {
#pragma unroll
        for (int i = 0; i < 4; ++i) scand[w][lane * 4 + i] = 4095 - (int)(c[i] & 0xFFFu);
    }
    sxn[w][lane] = xt[((size_t)b * N + n) * 64 + lane];
    __syncthreads();

    // exact fp32 rescore: lane = (candidate jc, c-half h)
    const float* xt_ = xt + (size_t)b * N * 64;
    const int jc = lane & 31, h = lane >> 5;
    const int mj = scand[w][jc];
    const float* xr = xt_ + (size_t)mj * 64 + h * 32;
    float acc = 0.f;
#pragma unroll
    for (int q8 = 0; q8 < 8; ++q8) {
        float4 g4 = *(const float4*)&xr[q8 * 4];
        float4 xn4 = *(const float4*)&sxn[w][h * 32 + q8 * 4];
        acc += g4.x * xn4.x + g4.y * xn4.y + g4.z * xn4.z + g4.w * xn4.w;
    }
    acc += __shfl_xor(acc, 32);
    float ex = 2.f * acc - xx[(size_t)b * N + mj];
    unsigned fu = __builtin_bit_cast(unsigned, ex);
    unsigned sf = fu ^ (unsigned)(((int)fu >> 31) | 0x80000000);
    u64 key = ((u64)sf << 12) | (u64)(4095 - mj);
    if (h) key = 0;                        // duplicate copy lives in lanes 32..63

    // descending bitonic sort of 32 u64 keys (lanes 0..31; halves isolated)
#pragma unroll
    for (int ls = 1; ls <= 5; ++ls) {
        const int s = 1 << ls;
        const bool lb = (lane & s) == 0;
#pragma unroll
        for (int dd = s >> 1; dd >= 1; dd >>= 1) {
            const bool km = ((lane & dd) == 0) == lb;
            u64 pv = __shfl_xor(key, dd);
            u64 mn = key < pv ? key : pv;
            u64 mx = key < pv ? pv : key;
            key = km ? mx : mn;
        }
    }
    int m_final = 4095 - (int)(key & 0xFFFu);   // lane r (<32) = r-th best exact

    // fused BN stats gather: lane = o
    const __half* ub = u + (size_t)b * N * O;
    size_t rowb = (size_t)b * N + n;
    float vv = __half2float(v[rowb * O + lane]);
    float gmax = -FLT_MAX, gmin = FLT_MAX, gs = 0.f, gs2 = 0.f;
    if (k == 20) {
        int mks[20];
#pragma unroll
        for (int kk = 0; kk < 20; ++kk) mks[kk] = __shfl(m_final, kk);
        float g[20];
#pragma unroll
        for (int kk = 0; kk < 20; ++kk)
            g[kk] = __half2float(ub[(size_t)mks[kk] * O + lane]);
#pragma unroll
        for (int kk = 0; kk < 20; ++kk) {
            gs += g[kk]; gs2 += g[kk] * g[kk];
            gmax = fmaxf(gmax, g[kk]); gmin = fminf(gmin, g[kk]);
        }
    } else {
        int mks[KMAX];
#pragma unroll
        for (int kk = 0; kk < KMAX; ++kk) mks[kk] = __shfl(m_final, kk);
        float g[KMAX];
#pragma unroll
        for (int kk = 0; kk < KMAX; ++kk)
            g[kk] = __half2float(ub[(size_t)mks[kk] * O + lane]);
#pragma unroll
        for (int kk = 0; kk < KMAX; ++kk) {
            if (kk < k) {
                gs += g[kk]; gs2 += g[kk] * g[kk];
                gmax = fmaxf(gmax, g[kk]); gmin = fminf(gmin, g[kk]);
            }
        }
    }
    float fk = (float)k;
    float s  = gs + fk * vv;
    float s2 = gs2 + 2.f * vv * gs + fk * vv * vv;
    ext[rowb * O + lane] = __halves2half2(__float2half(gmax + vv), __float2half(gmin + vv));
    rsum[t] = s; rsum2[t] = s2;
    __syncthreads();
    if (t < 64) {
        float a  = rsum[t] + rsum[t + 64] + rsum[t + 128] + rsum[t + 192];
        float a2 = rsum2[t] + rsum2[t + 64] + rsum2[t + 128] + rsum2[t + 192];
        float* sr = statsR + (size_t)(blockIdx.x & (NREP - 1)) * 128;
        atomicAdd(&sr[t], a);
        atomicAdd(&sr[64 + t], a2);
    }
}

// ---------- finalize BN affine (reduce NREP replicas) ----------
__global__ void ec_final(const float* __restrict__ statsR,
                         const float* __restrict__ gamma,
                         const float* __restrict__ beta,
                         const int* __restrict__ kptr,
                         float* __restrict__ scsh) {
    int o = threadIdx.x;                   // 64
    int k = *kptr;
    float s = 0.f, s2 = 0.f;
    for (int r = 0; r < NREP; ++r) {
        s  += statsR[r * 128 + o];
        s2 += statsR[r * 128 + 64 + o];
    }
    float M = (float)B * (float)N * (float)k;
    float mean = s / M;
    float var = s2 / M - mean * mean;
    var = fmaxf(var, 0.f);
    float sc = gamma[o] * rsqrtf(var + 1e-5f);
    float sh = beta[o] - mean * sc;
    scsh[o] = sc;
    scsh[64 + o] = sh;
}

// ---------- output: pick extreme by sc sign, BN + leaky, transpose ----------
__global__ __launch_bounds__(256) void ec_out(const __half2* __restrict__ ext,
                                              const float* __restrict__ scsh,
                                              float* __restrict__ out) {
    __shared__ float res[64][65];
    const int blk = blockIdx.x;            // B*N/64
    const int b = blk >> 6;
    const int n0 = (blk & 63) << 6;
    const int t = threadIdx.x;
    {
        const int o = t & 63, ni = t >> 6;
        float sc = scsh[o], sh = scsh[64 + o];
#pragma unroll 1
        for (int p = 0; p < 16; ++p) {
            int nl = ni * 16 + p;
            size_t a = ((size_t)b * N + n0 + nl) * O + o;
            __half2 e = ext[a];
            float y = (sc >= 0.f) ? __low2float(e) : __high2float(e);
            float z = sc * y + sh;
            res[nl][o] = (z >= 0.f) ? z : 0.2f * z;
        }
    }
    __syncthreads();
    {
        const int j = t & 63, oi = t >> 6;
#pragma unroll 1
        for (int p = 0; p < 16; ++p) {
            int o2 = oi * 16 + p;
            out[(size_t)b * O * N + (size_t)o2 * N + n0 + j] = res[j][o2];
        }
    }
}

extern "C" void kernel_launch(void* const* d_in, const int* in_sizes, int n_in,
                              void* d_out, int out_size, void* d_ws, size_t ws_size,
                              hipStream_t stream) {
    const float* x     = (const float*)d_in[0];
    const float* W     = (const float*)d_in[1];
    const float* gamma = (const float*)d_in[2];
    const float* beta  = (const float*)d_in[3];
    const int*   kptr  = (const int*)d_in[4];
    float* out = (float*)d_out;

    char* ws = (char*)d_ws;
    u32*    cand = (u32*)ws;    ws += (size_t)B * N * 32 * 8 * 4;  // 32 MB
    float*  xx   = (float*)ws;  ws += (size_t)B * N * 4;
    float*  xt   = (float*)ws;  ws += (size_t)B * N * C * 4;       // 8 MB
    u16*    xtb  = (u16*)ws;    ws += (size_t)B * N * C * 2;       // 4 MB
    __half* u_t  = (__half*)ws; ws += (size_t)B * N * O * 2;       // 4 MB
    __half* v_t  = (__half*)ws; ws += (size_t)B * N * O * 2;       // 4 MB
    __half2* ext = (__half2*)ws; ws += (size_t)B * N * O * 4;      // 8 MB
    float* statsR = (float*)ws; ws += (size_t)NREP * 128 * 4;      // 32 KB
    float* scsh  = (float*)ws;

    hipMemsetAsync(statsR, 0, NREP * 128 * 4, stream);
    ec_prep<<<B * N / 32, 256, 0, stream>>>(x, W, xx, xt, xtb, u_t, v_t);
    ec_gemm<<<dim3(N / 128, N / 128, B), 256, 0, stream>>>(xtb, xx, cand);
    ec_sel<<<dim3(N / 4, B), 256, 0, stream>>>(cand, xt, xx, u_t, v_t, kptr, ext, statsR);
    ec_final<<<1, 64, 0, stream>>>(statsR, gamma, beta, kptr, scsh);
    ec_out<<<B * N / 64, 256, 0, stream>>>(ext, scsh, out);
}

// Round 15
// 145.902 us; speedup vs baseline: 3.5543x; 1.0074x over previous
//
#include <hip/hip_runtime.h>
#include <hip/hip_fp16.h>
#include <float.h>

#define B 8
#define C 64
#define N 4096
#define O 64
#define KMAX 32
#define NREP 64   // stats replica buffers (atomic contention divider)

typedef unsigned short u16;
typedef unsigned int u32;
typedef unsigned long long u64;
typedef __attribute__((ext_vector_type(8))) u16 u16x8;
typedef __attribute__((ext_vector_type(8))) short bf16x8;
typedef __attribute__((ext_vector_type(4))) float f32x4;

__device__ __forceinline__ u16 f2bf(float f) {
    unsigned u = __builtin_bit_cast(unsigned, f);
    unsigned r = (u + 0x7FFFu + ((u >> 16) & 1)) >> 16;   // RTNE
    return (u16)r;
}

// ---------- fused prep: xt fp32, xtb bf16, xx, u/v fp16 ----------
__global__ __launch_bounds__(256) void ec_prep(const float* __restrict__ x,
                                               const float* __restrict__ W,
                                               float* __restrict__ xx,
                                               float* __restrict__ xt,
                                               u16* __restrict__ xtb,
                                               __half* __restrict__ u,
                                               __half* __restrict__ v) {
    __shared__ float xs[64][33];
    __shared__ __half2 Wp[C][65];
    __shared__ float rs[8][32];
    const int blk = blockIdx.x;            // B*N/32 = 1024
    const int b = blk >> 7;
    const int n0 = (blk & 127) << 5;
    const int t = threadIdx.x;
#pragma unroll
    for (int p = 0; p < 8; ++p) {
        int q = t + 256 * p; int c = q >> 5, j = q & 31;
        xs[c][j] = x[(size_t)b * C * N + (size_t)c * N + n0 + j];
    }
#pragma unroll
    for (int p = 0; p < 16; ++p) {
        int q = t + 256 * p; int o = q >> 6, c = q & 63;   // lanes: consecutive c
        float w1 = W[o * 128 + c];
        float w2 = W[o * 128 + 64 + c];
        Wp[c][o] = __floats2half2_rn(w1, w2 - w1);
    }
    __syncthreads();
    {
        const int j = t >> 3, g = t & 7;
        float vals[8]; float ss = 0.f;
#pragma unroll
        for (int i = 0; i < 8; ++i) { float f = xs[g * 8 + i][j]; vals[i] = f; ss += f * f; }
        rs[g][j] = ss;
        size_t rowb = ((size_t)b * N + n0 + j) * 64 + g * 8;
        float4 v0 = { vals[0], vals[1], vals[2], vals[3] };
        float4 v1 = { vals[4], vals[5], vals[6], vals[7] };
        *(float4*)&xt[rowb] = v0;
        *(float4*)&xt[rowb + 4] = v1;
        u16x8 h0;
#pragma unroll
        for (int i = 0; i < 8; ++i) h0[i] = f2bf(vals[i]);
        *(u16x8*)&xtb[rowb] = h0;
    }
    {
        const int o = t & 63, ji = t >> 6;
        float su[8] = {}, sv[8] = {};
#pragma unroll 1
        for (int c = 0; c < C; ++c) {
            __half2 wp = Wp[c][o];
            float w1 = __low2float(wp), wd = __high2float(wp);
#pragma unroll
            for (int p = 0; p < 8; ++p) {
                float xv = xs[c][ji + 4 * p];
                su[p] = fmaf(xv, w1, su[p]);
                sv[p] = fmaf(xv, wd, sv[p]);
            }
        }
#pragma unroll
        for (int p = 0; p < 8; ++p) {
            size_t base = ((size_t)b * N + n0 + ji + 4 * p) * O + o;
            u[base] = __float2half(su[p]);
            v[base] = __float2half(sv[p]);
        }
    }
    __syncthreads();
    if (t < 32) {
        float a = 0.f;
#pragma unroll
        for (int g = 0; g < 8; ++g) a += rs[g][t];
        xx[(size_t)b * N + n0 + t] = a;
    }
}

// ---------- in-register compare-exchange (descending: first arg keeps max) ----------
#define CXD(a, b) { u32 mx_ = max(a, b); b = min(a, b); a = mx_; }
// Batcher optimal 19-comparator sort-8, descending
#define BSORT8(e0,e1,e2,e3,e4,e5,e6,e7) { \
    CXD(e0,e1) CXD(e2,e3) CXD(e4,e5) CXD(e6,e7) \
    CXD(e0,e2) CXD(e1,e3) CXD(e4,e6) CXD(e5,e7) \
    CXD(e1,e2) CXD(e5,e6) CXD(e0,e4) CXD(e3,e7) \
    CXD(e1,e5) CXD(e2,e6) \
    CXD(e1,e4) CXD(e3,e6) \
    CXD(e2,e4) CXD(e3,e5) \
    CXD(e3,e4) }
// merge sorted-8 e into sorted-8 t keeping top-8 (8 max + 12 CX clean)
#define MERGETOP8(t0,t1,t2,t3,t4,t5,t6,t7, e0,e1,e2,e3,e4,e5,e6,e7) { \
    t0 = max(t0, e7); t1 = max(t1, e6); t2 = max(t2, e5); t3 = max(t3, e4); \
    t4 = max(t4, e3); t5 = max(t5, e2); t6 = max(t6, e1); t7 = max(t7, e0); \
    CXD(t0,t4) CXD(t1,t5) CXD(t2,t6) CXD(t3,t7) \
    CXD(t0,t2) CXD(t1,t3) CXD(t4,t6) CXD(t5,t7) \
    CXD(t0,t1) CXD(t2,t3) CXD(t4,t5) CXD(t6,t7) }

// ---------- MFMA distance + fused per-(row,128-col-chunk) top-8 ----------
// Key: dvp = 2*acc - xm + 2560 in (2230,2780) -> single binade [2048,4096)
// -> (u16)(bits>>7) is monotone in d, granularity 2^-5.
// cand[((b*N+row)*32 + chunk)*8 + s] : packed u32 = (key16<<12)|(4095-m)
__global__ __launch_bounds__(256) void ec_gemm(const u16* __restrict__ xtb,
                                               const float* __restrict__ xx,
                                               u32* __restrict__ cand) {
    __shared__ u16 lds[18432 + 8];
    const int t = threadIdx.x;
    const int m0 = blockIdx.x * 128, n0 = blockIdx.y * 128;
    const int b = blockIdx.z;
    const u16* xa = xtb + (size_t)b * N * 64;
#pragma unroll
    for (int p = 0; p < 4; ++p) {
        int q = t + 256 * p;
        int row = q >> 3, ch = q & 7;
        int by = (row * 128 + ch * 16) ^ ((row & 7) << 4);
        *(u16x8*)((char*)lds + by) = *(const u16x8*)&xa[(size_t)(n0 + row) * 64 + ch * 8];
        *(u16x8*)((char*)lds + 16384 + by) = *(const u16x8*)&xa[(size_t)(m0 + row) * 64 + ch * 8];
    }
    __syncthreads();
    const int w = t >> 6, lane = t & 63;
    const int wr = w >> 1, wc = w & 1;
    const int fr = lane & 15, fg = lane >> 4;
    f32x4 acc[4][4] = {};
#pragma unroll
    for (int ks = 0; ks < 2; ++ks) {
        bf16x8 af[4], bg[4];
#pragma unroll
        for (int fi = 0; fi < 4; ++fi) {
            int rowA = 64 * wr + 16 * fi + fr;
            int byA = (rowA * 128 + ks * 64 + fg * 16) ^ ((rowA & 7) << 4);
            af[fi] = *(const bf16x8*)((const char*)lds + byA);
            int rowB = 64 * wc + 16 * fi + fr;
            int byB = (rowB * 128 + ks * 64 + fg * 16) ^ ((rowB & 7) << 4);
            bg[fi] = *(const bf16x8*)((const char*)lds + 16384 + byB);
        }
#pragma unroll
        for (int fi = 0; fi < 4; ++fi)
#pragma unroll
            for (int fj = 0; fj < 4; ++fj)
                acc[fi][fj] = __builtin_amdgcn_mfma_f32_16x16x32_bf16(af[fi], bg[fj], acc[fi][fj], 0, 0, 0);
    }
    float xmK[4];
#pragma unroll
    for (int fj = 0; fj < 4; ++fj)
        xmK[fj] = 2560.f - xx[(size_t)b * N + m0 + 64 * wc + 16 * fj + fr];
    __syncthreads();                        // staging LDS dead; reuse for epilogue
    u16* ep = lds + w * 4608;               // 64 rows x stride 72 u16 (144 B)
#pragma unroll
    for (int fi = 0; fi < 4; ++fi)
#pragma unroll
        for (int fj = 0; fj < 4; ++fj)
#pragma unroll
            for (int r = 0; r < 4; ++r) {
                float dvp = fmaf(2.f, acc[fi][fj][r], xmK[fj]);   // in (2230,2780)
                u32 bits = __builtin_bit_cast(u32, dvp);
                int row = 16 * fi + fg * 4 + r, col = 16 * fj + fr;
                ep[row * 72 + col] = (u16)(bits >> 7);            // monotone key
            }
    __syncthreads();
    // per-lane: row = lane; sorting-network top-8 over own 64 cols
    const u16* myrow = lds + w * 4608 + lane * 72;
    const int mbase = m0 + (wc << 6);
    const u32 invb = (u32)(4095 - mbase);   // wave-uniform
    u32 t0, t1, t2, t3, t4, t5, t6, t7;
    {
        u16x8 q = *(const u16x8*)&myrow[0];
        t0 = ((u32)q[0] << 12) | (invb - 0); t1 = ((u32)q[1] << 12) | (invb - 1);
        t2 = ((u32)q[2] << 12) | (invb - 2); t3 = ((u32)q[3] << 12) | (invb - 3);
        t4 = ((u32)q[4] << 12) | (invb - 4); t5 = ((u32)q[5] << 12) | (invb - 5);
        t6 = ((u32)q[6] << 12) | (invb - 6); t7 = ((u32)q[7] << 12) | (invb - 7);
        BSORT8(t0, t1, t2, t3, t4, t5, t6, t7)
    }
#pragma unroll
    for (int g = 1; g < 8; ++g) {
        u16x8 q = *(const u16x8*)&myrow[g * 8];
        const u32 inv0 = invb - (u32)(g * 8);  // wave-uniform
        u32 e0 = ((u32)q[0] << 12) | (inv0 - 0), e1 = ((u32)q[1] << 12) | (inv0 - 1);
        u32 e2 = ((u32)q[2] << 12) | (inv0 - 2), e3 = ((u32)q[3] << 12) | (inv0 - 3);
        u32 e4 = ((u32)q[4] << 12) | (inv0 - 4), e5 = ((u32)q[5] << 12) | (inv0 - 5);
        u32 e6 = ((u32)q[6] << 12) | (inv0 - 6), e7 = ((u32)q[7] << 12) | (inv0 - 7);
        BSORT8(e0, e1, e2, e3, e4, e5, e6, e7)
        MERGETOP8(t0, t1, t2, t3, t4, t5, t6, t7, e0, e1, e2, e3, e4, e5, e6, e7)
    }
    // cross-warp merge: wc=1 half into wc=0 half -> top-8 per 128-col chunk
    __syncthreads();                        // all myrow reads done
    u32* mbuf = (u32*)lds;                  // 4 KB reuse
    if (wc) {
        u32* mp = mbuf + (size_t)((wr << 6) | lane) * 8;
        uint4 w0 = { t0, t1, t2, t3 }, w1 = { t4, t5, t6, t7 };
        *(uint4*)mp = w0;
        *(uint4*)(mp + 4) = w1;
    }
    __syncthreads();
    if (!wc) {
        const u32* mp = mbuf + (size_t)((wr << 6) | lane) * 8;
        uint4 b0 = *(const uint4*)mp, b1 = *(const uint4*)(mp + 4);
        u32 e0 = b0.x, e1 = b0.y, e2 = b0.z, e3 = b0.w;
        u32 e4 = b1.x, e5 = b1.y, e6 = b1.z, e7 = b1.w;
        MERGETOP8(t0, t1, t2, t3, t4, t5, t6, t7, e0, e1, e2, e3, e4, e5, e6, e7)
        const int row_g = n0 + 64 * wr + lane;
        u32* cp = cand + (((size_t)b * N + row_g) * 32 + blockIdx.x) * 8;
        uint4 w0 = { t0, t1, t2, t3 }, w1 = { t4, t5, t6, t7 };
        *(uint4*)cp = w0;
        *(uint4*)(cp + 4) = w1;
    }
}

// ---------- distributed merge-tree helpers (4 keys/lane) ----------
#define CX4(i, j) { u32 mn_ = min(c[i], c[j]); c[i] = max(c[i], c[j]); c[j] = mn_; }
#define CLEAN4IN() { CX4(0,2) CX4(1,3) CX4(0,1) CX4(2,3) }
#define DSTEP(xorm, bit) { \
    u32 pr_[4]; \
    _Pragma("unroll") for (int i_ = 0; i_ < 4; ++i_) pr_[i_] = __shfl_xor(c[i_], xorm); \
    bool km_ = (lane & (bit)) == 0; \
    _Pragma("unroll") for (int i_ = 0; i_ < 4; ++i_) \
        c[i_] = km_ ? max(c[i_], pr_[i_]) : min(c[i_], pr_[i_]); }

// ---------- sel: merge-tree top-32 -> exact rescore -> sort-32 -> stats ----------
__global__ __launch_bounds__(256) void ec_sel(const u32* __restrict__ cand,
                                              const float* __restrict__ xt,
                                              const float* __restrict__ xx,
                                              const __half* __restrict__ u,
                                              const __half* __restrict__ v,
                                              const int* __restrict__ kptr,
                                              __half2* __restrict__ ext,
                                              float* __restrict__ statsR) {
    __shared__ float sxn[4][64];
    __shared__ int scand[4][32];
    __shared__ float rsum[256], rsum2[256];
    const int t = threadIdx.x, w = t >> 6, lane = t & 63;
    const int b = blockIdx.y;
    const int n = blockIdx.x * 4 + w;
    const int k = *kptr;

    // lane pair (2c,2c+1) holds chunk c's sorted-8; rank = 4*(lane&1)+reg
    const u32* cp = cand + (((size_t)b * N + n) * 32 + (lane >> 1)) * 8 + (lane & 1) * 4;
    uint4 a0 = *(const uint4*)cp;
    u32 c[4] = { a0.x, a0.y, a0.z, a0.w };

    // L1 (xor2): chunk pairs -> sorted-16 over 4 lanes
    {
        u32 pr[4];
#pragma unroll
        for (int i = 0; i < 4; ++i) pr[i] = __shfl_xor(c[3 - i], 3);
        bool lo = (lane & 2) == 0;
#pragma unroll
        for (int i = 0; i < 4; ++i) {
            u32 mx = max(c[i], pr[i]), mn = min(c[i], pr[i]);
            c[i] = lo ? mx : mn;
        }
        DSTEP(1, 1)
        CLEAN4IN()
    }
    // L2 (xor4): -> sorted-32 over 8 lanes
    {
        u32 pr[4];
#pragma unroll
        for (int i = 0; i < 4; ++i) pr[i] = __shfl_xor(c[3 - i], 7);
        bool lo = (lane & 4) == 0;
#pragma unroll
        for (int i = 0; i < 4; ++i) {
            u32 mx = max(c[i], pr[i]), mn = min(c[i], pr[i]);
            c[i] = lo ? mx : mn;
        }
        DSTEP(2, 2) DSTEP(1, 1)
        CLEAN4IN()
    }
    // L3-5: top-32 halver + bitonic-32 clean (8-lane groups 8/16/32 apart)
#define MT32(mask) { \
        u32 pr_[4]; \
        _Pragma("unroll") for (int i_ = 0; i_ < 4; ++i_) pr_[i_] = __shfl_xor(c[3 - i_], mask); \
        _Pragma("unroll") for (int i_ = 0; i_ < 4; ++i_) c[i_] = max(c[i_], pr_[i_]); \
        DSTEP(4, 4) DSTEP(2, 2) DSTEP(1, 1) CLEAN4IN() }
    MT32(15)
    MT32(23)
    MT32(39)
#undef MT32

    // lanes 0-7 hold global top-32 sorted desc: rank = 4*lane + reg
    if (lane < 8) {
#pragma unroll
        for (int i = 0; i < 4; ++i) scand[w][lane * 4 + i] = 4095 - (int)(c[i] & 0xFFFu);
    }
    sxn[w][lane] = xt[((size_t)b * N + n) * 64 + lane];
    __syncthreads();

    // exact fp32 rescore: lane = (candidate jc, c-half h)
    const float* xt_ = xt + (size_t)b * N * 64;
    const int jc = lane & 31, h = lane >> 5;
    const int mj = scand[w][jc];
    const float* xr = xt_ + (size_t)mj * 64 + h * 32;
    float acc = 0.f;
#pragma unroll
    for (int q8 = 0; q8 < 8; ++q8) {
        float4 g4 = *(const float4*)&xr[q8 * 4];
        float4 xn4 = *(const float4*)&sxn[w][h * 32 + q8 * 4];
        acc += g4.x * xn4.x + g4.y * xn4.y + g4.z * xn4.z + g4.w * xn4.w;
    }
    acc += __shfl_xor(acc, 32);
    float ex = 2.f * acc - xx[(size_t)b * N + mj];
    unsigned fu = __builtin_bit_cast(unsigned, ex);
    unsigned sf = fu ^ (unsigned)(((int)fu >> 31) | 0x80000000);
    u64 key = ((u64)sf << 12) | (u64)(4095 - mj);
    if (h) key = 0;                        // duplicate copy lives in lanes 32..63

    // descending bitonic sort of 32 u64 keys (lanes 0..31; halves isolated)
#pragma unroll
    for (int ls = 1; ls <= 5; ++ls) {
        const int s = 1 << ls;
        const bool lb = (lane & s) == 0;
#pragma unroll
        for (int dd = s >> 1; dd >= 1; dd >>= 1) {
            const bool km = ((lane & dd) == 0) == lb;
            u64 pv = __shfl_xor(key, dd);
            u64 mn = key < pv ? key : pv;
            u64 mx = key < pv ? pv : key;
            key = km ? mx : mn;
        }
    }
    int m_final = 4095 - (int)(key & 0xFFFu);   // lane r (<32) = r-th best exact

    // publish exact-sorted indices for vectorized broadcast gather
    if (lane < KMAX) scand[w][lane] = m_final;

    // fused BN stats gather: lane = o
    const __half* ub = u + (size_t)b * N * O;
    size_t rowb = (size_t)b * N + n;
    float vv = __half2float(v[rowb * O + lane]);
    float gmax = -FLT_MAX, gmin = FLT_MAX, gs = 0.f, gs2 = 0.f;
    if (k == 20) {
        const int4* ip = (const int4*)&scand[w][0];
        int4 q0 = ip[0], q1 = ip[1], q2 = ip[2], q3 = ip[3], q4 = ip[4];
        float g[20];
        g[0]  = __half2float(ub[(size_t)q0.x * O + lane]);
        g[1]  = __half2float(ub[(size_t)q0.y * O + lane]);
        g[2]  = __half2float(ub[(size_t)q0.z * O + lane]);
        g[3]  = __half2float(ub[(size_t)q0.w * O + lane]);
        g[4]  = __half2float(ub[(size_t)q1.x * O + lane]);
        g[5]  = __half2float(ub[(size_t)q1.y * O + lane]);
        g[6]  = __half2float(ub[(size_t)q1.z * O + lane]);
        g[7]  = __half2float(ub[(size_t)q1.w * O + lane]);
        g[8]  = __half2float(ub[(size_t)q2.x * O + lane]);
        g[9]  = __half2float(ub[(size_t)q2.y * O + lane]);
        g[10] = __half2float(ub[(size_t)q2.z * O + lane]);
        g[11] = __half2float(ub[(size_t)q2.w * O + lane]);
        g[12] = __half2float(ub[(size_t)q3.x * O + lane]);
        g[13] = __half2float(ub[(size_t)q3.y * O + lane]);
        g[14] = __half2float(ub[(size_t)q3.z * O + lane]);
        g[15] = __half2float(ub[(size_t)q3.w * O + lane]);
        g[16] = __half2float(ub[(size_t)q4.x * O + lane]);
        g[17] = __half2float(ub[(size_t)q4.y * O + lane]);
        g[18] = __half2float(ub[(size_t)q4.z * O + lane]);
        g[19] = __half2float(ub[(size_t)q4.w * O + lane]);
#pragma unroll
        for (int kk = 0; kk < 20; ++kk) {
            gs += g[kk]; gs2 += g[kk] * g[kk];
            gmax = fmaxf(gmax, g[kk]); gmin = fminf(gmin, g[kk]);
        }
    } else {
        int mks[KMAX];
#pragma unroll
        for (int kk = 0; kk < KMAX; ++kk) mks[kk] = __shfl(m_final, kk);
        float g[KMAX];
#pragma unroll
        for (int kk = 0; kk < KMAX; ++kk)
            g[kk] = __half2float(ub[(size_t)mks[kk] * O + lane]);
#pragma unroll
        for (int kk = 0; kk < KMAX; ++kk) {
            if (kk < k) {
                gs += g[kk]; gs2 += g[kk] * g[kk];
                gmax = fmaxf(gmax, g[kk]); gmin = fminf(gmin, g[kk]);
            }
        }
    }
    float fk = (float)k;
    float s  = gs + fk * vv;
    float s2 = gs2 + 2.f * vv * gs + fk * vv * vv;
    ext[rowb * O + lane] = __halves2half2(__float2half(gmax + vv), __float2half(gmin + vv));
    rsum[t] = s; rsum2[t] = s2;
    __syncthreads();
    if (t < 64) {
        float a  = rsum[t] + rsum[t + 64] + rsum[t + 128] + rsum[t + 192];
        float a2 = rsum2[t] + rsum2[t + 64] + rsum2[t + 128] + rsum2[t + 192];
        float* sr = statsR + (size_t)(blockIdx.x & (NREP - 1)) * 128;
        atomicAdd(&sr[t], a);
        atomicAdd(&sr[64 + t], a2);
    }
}

// ---------- output: replica-reduce BN affine + pick extreme + leaky + transpose ----------
__global__ __launch_bounds__(256) void ec_out(const __half2* __restrict__ ext,
                                              const float* __restrict__ statsR,
                                              const float* __restrict__ gamma,
                                              const float* __restrict__ beta,
                                              const int* __restrict__ kptr,
                                              float* __restrict__ out) {
    __shared__ float res[64][65];
    __shared__ float scs[64], shs[64];
    const int blk = blockIdx.x;            // B*N/64
    const int b = blk >> 6;
    const int n0 = (blk & 63) << 6;
    const int t = threadIdx.x;
    if (t < 64) {
        float s = 0.f, s2 = 0.f;
#pragma unroll 8
        for (int r = 0; r < NREP; ++r) {
            s  += statsR[r * 128 + t];
            s2 += statsR[r * 128 + 64 + t];
        }
        int k = *kptr;
        float M = (float)B * (float)N * (float)k;
        float mean = s / M;
        float var = fmaxf(s2 / M - mean * mean, 0.f);
        float sc = gamma[t] * rsqrtf(var + 1e-5f);
        scs[t] = sc;
        shs[t] = beta[t] - mean * sc;
    }
    __syncthreads();
    {
        const int o = t & 63, ni = t >> 6;
        float sc = scs[o], sh = shs[o];
#pragma unroll 1
        for (int p = 0; p < 16; ++p) {
            int nl = ni * 16 + p;
            size_t a = ((size_t)b * N + n0 + nl) * O + o;
            __half2 e = ext[a];
            float y = (sc >= 0.f) ? __low2float(e) : __high2float(e);
            float z = sc * y + sh;
            res[nl][o] = (z >= 0.f) ? z : 0.2f * z;
        }
    }
    __syncthreads();
    {
        const int j = t & 63, oi = t >> 6;
#pragma unroll 1
        for (int p = 0; p < 16; ++p) {
            int o2 = oi * 16 + p;
            out[(size_t)b * O * N + (size_t)o2 * N + n0 + j] = res[j][o2];
        }
    }
}

extern "C" void kernel_launch(void* const* d_in, const int* in_sizes, int n_in,
                              void* d_out, int out_size, void* d_ws, size_t ws_size,
                              hipStream_t stream) {
    const float* x     = (const float*)d_in[0];
    const float* W     = (const float*)d_in[1];
    const float* gamma = (const float*)d_in[2];
    const float* beta  = (const float*)d_in[3];
    const int*   kptr  = (const int*)d_in[4];
    float* out = (float*)d_out;

    char* ws = (char*)d_ws;
    u32*    cand = (u32*)ws;    ws += (size_t)B * N * 32 * 8 * 4;  // 32 MB
    float*  xx   = (float*)ws;  ws += (size_t)B * N * 4;
    float*  xt   = (float*)ws;  ws += (size_t)B * N * C * 4;       // 8 MB
    u16*    xtb  = (u16*)ws;    ws += (size_t)B * N * C * 2;       // 4 MB
    __half* u_t  = (__half*)ws; ws += (size_t)B * N * O * 2;       // 4 MB
    __half* v_t  = (__half*)ws; ws += (size_t)B * N * O * 2;       // 4 MB
    __half2* ext = (__half2*)ws; ws += (size_t)B * N * O * 4;      // 8 MB
    float* statsR = (float*)ws; ws += (size_t)NREP * 128 * 4;      // 32 KB
    (void)ws;

    hipMemsetAsync(statsR, 0, NREP * 128 * 4, stream);
    ec_prep<<<B * N / 32, 256, 0, stream>>>(x, W, xx, xt, xtb, u_t, v_t);
    ec_gemm<<<dim3(N / 128, N / 128, B), 256, 0, stream>>>(xtb, xx, cand);
    ec_sel<<<dim3(N / 4, B), 256, 0, stream>>>(cand, xt, xx, u_t, v_t, kptr, ext, statsR);
    ec_out<<<B * N / 64, 256, 0, stream>>>(ext, statsR, gamma, beta, kptr, out);
}